// Round 21
// baseline (626.697 us; speedup 1.0000x reference)
//
#include <hip/hip_runtime.h>
#include <cstdint>

#define HW 131072        // H*W
#define S_ELEMS 16777216 // B*C*H*W

typedef __attribute__((ext_vector_type(8))) _Float16 f16x8;
typedef __attribute__((ext_vector_type(4))) _Float16 f16x4;
typedef __attribute__((ext_vector_type(4))) float f32x4;

__device__ __forceinline__ float h2f(unsigned short u) {
  return (float)__builtin_bit_cast(_Float16, u);
}
__device__ __forceinline__ unsigned short f2h(float f) {
  return __builtin_bit_cast(unsigned short, (_Float16)f);
}
// M32 bank swizzle: XOR col 8-blocks by row-class; kills j/j+8/j+16/j+24 bank aliasing
// while keeping 8-float blocks contiguous (float4-aligned reads still valid).
__device__ __forceinline__ int msw(int r, int c) {
  return r * 68 + (c ^ (((r >> 3) & 3) << 3));
}
// attn K-tile row stride in ushorts: 76 (38 words; 6*l15 mod 32 hits 16 distinct banks
// -> QK^T b128 fragment reads conflict-free; 72 gave 8-way: (4*l15+4*lg) mod 32)
#define KST 76

// ---------------- BN stats stage 1: partial sums (2 sides x 64 c x 16 slabs) ----------------
__global__ __launch_bounds__(256) void bn_part_k(const float* __restrict__ xL,
                                                 const float* __restrict__ xR,
                                                 float2* __restrict__ partial) {
  int bid = blockIdx.x;
  int side = bid >> 10, rest = bid & 1023;
  int c = rest >> 4, sl = rest & 15;
  const float* x = side ? xR : xL;
  const float4* p = (const float4*)(x + ((size_t)((sl >> 3) * 64 + c)) * HW + (size_t)(sl & 7) * 16384);
  float s1 = 0.f, s2 = 0.f;
  for (int i = threadIdx.x; i < 4096; i += 256) {
    float4 v = p[i];
    s1 += v.x + v.y + v.z + v.w;
    s2 += v.x * v.x + v.y * v.y + v.z * v.z + v.w * v.w;
  }
  for (int m = 32; m; m >>= 1) {
    s1 += __shfl_xor(s1, m, 64);
    s2 += __shfl_xor(s2, m, 64);
  }
  __shared__ float r1[4], r2[4];
  int wv = threadIdx.x >> 6;
  if ((threadIdx.x & 63) == 0) { r1[wv] = s1; r2[wv] = s2; }
  __syncthreads();
  if (threadIdx.x == 0) {
    partial[bid] = make_float2(r1[0] + r1[1] + r1[2] + r1[3], r2[0] + r2[1] + r2[2] + r2[3]);
  }
}

// ---------------- BN stats stage 2: finalize scale/shift ----------------
__global__ __launch_bounds__(128) void bn_fin_k(const float2* __restrict__ partial,
                                                const float* __restrict__ gamma,
                                                const float* __restrict__ beta,
                                                float* __restrict__ stats) {
  int tid = threadIdx.x;  // 0..127: side*64 + c
  int side = tid >> 6, c = tid & 63;
  float s1 = 0.f, s2 = 0.f;
  const float2* p = partial + (side * 1024 + c * 16);
  for (int s = 0; s < 16; ++s) { float2 v = p[s]; s1 += v.x; s2 += v.y; }
  float mu = s1 / 262144.f;
  float var = s2 / 262144.f - mu * mu;
  float rs = rsqrtf(var + 1e-5f);
  float sc = rs * gamma[c];
  stats[side * 128 + c] = sc;
  stats[side * 128 + 64 + c] = beta[c] - mu * sc;
}

// ---------------- conv1 via MFMA implicit GEMM: bn(x) fp16 -> 9-tap MFMA -> leaky -> t fp16 --
__global__ __launch_bounds__(256) void conv1_k(const float* __restrict__ xL,
                                               const float* __restrict__ xR,
                                               const float* __restrict__ wgt,
                                               const float* __restrict__ bias,
                                               const float* __restrict__ stats,
                                               unsigned short* __restrict__ tL,
                                               unsigned short* __restrict__ tR) {
  // ci-stride 372 ushorts -> fragment reads bank-spread (same as conv2)
  __shared__ __align__(16) unsigned short sInH[16 * 372];
  __shared__ __align__(16) float sW1r[2304];  // raw w1 [o][ci][9]
  __shared__ float sB1[16], sSc[16], sSh[16];
  int bid = blockIdx.x;
  int side = bid >> 12, rest = bid & 4095;
  int tw = rest & 15, th = (rest >> 4) & 31, g = (rest >> 9) & 3, b = rest >> 11;
  const float* in = side ? xR : xL;
  unsigned short* out = side ? tR : tL;
  const float* ss = stats + side * 128;
  int tid = threadIdx.x;
  const int lane = tid & 63, wv = tid >> 6;
  const int l15 = lane & 15, lg = lane >> 4;

  for (int e = tid; e < 2304; e += 256) sW1r[e] = wgt[g * 2304 + e];
  if (tid < 16) {
    sB1[tid] = bias[g * 16 + tid];
    sSc[tid] = ss[g * 16 + tid];
    sSh[tid] = ss[64 + g * 16 + tid];
  }
  __syncthreads();  // RACE FIX: sSc/sSh visible before staging reads them
  int h0 = th * 8 - 1, w0 = tw * 32 - 1;
  const float* inb = in + ((size_t)(b * 64 + g * 16)) * HW;
  for (int e = tid; e < 5440; e += 256) {
    int ci = e / 340, rem = e - ci * 340, r = rem / 34, c = rem - r * 34;
    int h = h0 + r, w = w0 + c;
    unsigned short v = 0;
    if ((unsigned)h < 256u && (unsigned)w < 512u) {
      v = f2h(inb[(size_t)ci * HW + h * 512 + w] * sSc[ci] + sSh[ci]);
    }
    sInH[ci * 372 + r * 36 + c] = v;
  }
  __syncthreads();

  // hoist W1 tap fragments (hi/lo): A-frag lane holds W[oc=l15][ci=4lg+i]
  f16x4 W1H[9], W1L[9];
#pragma unroll
  for (int tap = 0; tap < 9; ++tap) {
#pragma unroll
    for (int i = 0; i < 4; ++i) {
      float f = sW1r[l15 * 144 + (4 * lg + i) * 9 + tap];
      _Float16 h = (_Float16)f;
      W1H[tap][i] = h;
      W1L[tap][i] = (_Float16)(f - (float)h);
    }
  }
  float b14[4];
#pragma unroll
  for (int r = 0; r < 4; ++r) b14[r] = sB1[4 * lg + r];

  // per 16-px column block: 9-tap MFMA -> leaky -> f2h -> planar store
#pragma unroll
  for (int j = 0; j < 4; ++j) {
    int ct = 4 * wv + j;
    int px = ct * 16 + l15;
    int prow = px >> 5, pcol = px & 31;
    const unsigned short* p0 = sInH + (4 * lg) * 372 + prow * 36 + pcol;
    f32x4 acc;
#pragma unroll
    for (int r = 0; r < 4; ++r) acc[r] = b14[r];
#pragma unroll
    for (int kh = 0; kh < 3; ++kh) {
#pragma unroll
      for (int kw = 0; kw < 3; ++kw) {
        int toff = kh * 36 + kw;
        f16x4 it;
#pragma unroll
        for (int i = 0; i < 4; ++i)
          it[i] = __builtin_bit_cast(_Float16, p0[i * 372 + toff]);
        acc = __builtin_amdgcn_mfma_f32_16x16x16f16(W1H[kh * 3 + kw], it, acc, 0, 0, 0);
        acc = __builtin_amdgcn_mfma_f32_16x16x16f16(W1L[kh * 3 + kw], it, acc, 0, 0, 0);
      }
    }
    int hpix = th * 8 + prow, wpix = tw * 32 + pcol;
    size_t rowoff = (size_t)hpix * 512 + wpix;
#pragma unroll
    for (int r = 0; r < 4; ++r) {
      float a = acc[r];
      a = a > 0.f ? a : 0.1f * a;
      out[((size_t)(b * 64 + g * 16 + 4 * lg + r)) * HW + rowoff] = f2h(a);
    }
  }
}

// ---------------- fused conv2(MFMA implicit GEMM) + residual + qkv(MFMA); both sides --------
__global__ __launch_bounds__(256) void conv2_qkv_k(
    const unsigned short* __restrict__ tL, const unsigned short* __restrict__ tR,
    const float* __restrict__ xL, const float* __restrict__ xR,
    const float* __restrict__ w2g, const float* __restrict__ b2g,
    const float* __restrict__ wq, const float* __restrict__ bq,
    const float* __restrict__ stats,
    float* __restrict__ qnL, float* __restrict__ qnR,
    float* __restrict__ knL, float* __restrict__ knR,
    unsigned short* __restrict__ vnL, unsigned short* __restrict__ vnR) {
  __shared__ __align__(16) unsigned short sInH[16 * 372];  // conv1-out fp16 tile +1 halo
  __shared__ __align__(16) float sW2r[2304];               // raw w2 [o][ci][9]
  __shared__ __align__(16) float sWq[768];
  __shared__ float sB2[16], sBq[48], sSc[16], sSh[16];

  int bid = blockIdx.x;
  int side = bid >> 12, rest = bid & 4095;
  int tw = rest & 15, th = (rest >> 4) & 31, g = (rest >> 9) & 3, b = rest >> 11;
  const unsigned short* t = side ? tR : tL;
  const float* x = side ? xR : xL;
  float* qn = side ? qnR : qnL;
  float* kn = side ? knR : knL;
  unsigned short* vn = side ? vnR : vnL;
  const float* ss = stats + side * 128;
  int tid = threadIdx.x;
  const int lane = tid & 63, wv = tid >> 6;
  const int l15 = lane & 15, lg = lane >> 4;

  // early residual prefetch (T14), in D layout: oc=4lg+r, px=ct*16+l15
  float resx[4][4];
#pragma unroll
  for (int j = 0; j < 4; ++j) {
    int px = (4 * wv + j) * 16 + l15;
    int hpix = th * 8 + (px >> 5), wpix = tw * 32 + (px & 31);
    size_t rowoff = (size_t)hpix * 512 + wpix;
#pragma unroll
    for (int r = 0; r < 4; ++r)
      resx[j][r] = x[((size_t)(b * 64 + g * 16 + 4 * lg + r)) * HW + rowoff];
  }

  // stage weights / biases / bn scale-shift
  for (int e = tid; e < 2304; e += 256) sW2r[e] = w2g[g * 2304 + e];
  for (int e = tid; e < 768; e += 256) {
    int oo = e >> 4, ci = e & 15;
    sWq[e] = wq[(g * 48 + oo) * 16 + ci];
  }
  if (tid < 48) sBq[tid] = bq[g * 48 + tid];
  if (tid < 16) {
    sB2[tid] = b2g[g * 16 + tid];
    sSc[tid] = ss[g * 16 + tid];
    sSh[tid] = ss[64 + g * 16 + tid];
  }

  // stage conv1-out tile (1-halo) from global fp16 -> LDS fp16 (padded stride)
  int h0 = th * 8 - 1, w0 = tw * 32 - 1;
  const unsigned short* inb = t + ((size_t)(b * 64 + g * 16)) * HW;
  for (int e = tid; e < 5440; e += 256) {
    int ci = e / 340, rem = e - ci * 340, r = rem / 34, c = rem - r * 34;
    int h = h0 + r, w = w0 + c;
    unsigned short v = 0;
    if ((unsigned)h < 256u && (unsigned)w < 512u) {
      v = inb[(size_t)ci * HW + h * 512 + w];
    }
    sInH[ci * 372 + r * 36 + c] = v;
  }
  __syncthreads();  // weights + tile staged (single barrier; nothing else writes LDS)

  // hoist A fragments: W2 taps (hi/lo split) + Wq (hi/lo)
  f16x4 W2H[9], W2L[9];
#pragma unroll
  for (int tap = 0; tap < 9; ++tap) {
#pragma unroll
    for (int i = 0; i < 4; ++i) {
      float f = sW2r[l15 * 144 + (4 * lg + i) * 9 + tap];
      _Float16 h = (_Float16)f;
      W2H[tap][i] = h;
      W2L[tap][i] = (_Float16)(f - (float)h);
    }
  }
  f16x4 WqH[3], WqL[3];
#pragma unroll
  for (int rt = 0; rt < 3; ++rt) {
    float4 wvv = *(const float4*)(sWq + (rt * 16 + l15) * 16 + 4 * lg);
#pragma unroll
    for (int i = 0; i < 4; ++i) {
      float f = ((float*)&wvv)[i];
      _Float16 h = (_Float16)f;
      WqH[rt][i] = h;
      WqL[rt][i] = (_Float16)(f - (float)h);
    }
  }
  float sc4[4], sh4[4], b24[4];
#pragma unroll
  for (int r = 0; r < 4; ++r) {
    sc4[r] = sSc[4 * lg + r];
    sh4[r] = sSh[4 * lg + r];
    b24[r] = sB2[4 * lg + r];
  }

  // per 16-px column block: conv2 MFMA -> residual -> split -> qkv MFMA -> store
#pragma unroll
  for (int j = 0; j < 4; ++j) {
    int ct = 4 * wv + j;
    int px = ct * 16 + l15;
    int prow = px >> 5, pcol = px & 31;
    const unsigned short* p0 = sInH + (4 * lg) * 372 + prow * 36 + pcol;
    f32x4 acc;
#pragma unroll
    for (int r = 0; r < 4; ++r) acc[r] = b24[r];
#pragma unroll
    for (int kh = 0; kh < 3; ++kh) {
#pragma unroll
      for (int kw = 0; kw < 3; ++kw) {
        int toff = kh * 36 + kw;
        f16x4 it;
#pragma unroll
        for (int i = 0; i < 4; ++i)
          it[i] = __builtin_bit_cast(_Float16, p0[i * 372 + toff]);
        acc = __builtin_amdgcn_mfma_f32_16x16x16f16(W2H[kh * 3 + kw], it, acc, 0, 0, 0);
        acc = __builtin_amdgcn_mfma_f32_16x16x16f16(W2L[kh * 3 + kw], it, acc, 0, 0, 0);
      }
    }
#pragma unroll
    for (int r = 0; r < 4; ++r) acc[r] += resx[j][r] * sc4[r] + sh4[r];
    // split r fragment (conv2 D == qkv B mapping: lane holds ci=4lg+i at px)
    f16x4 rh, rl;
#pragma unroll
    for (int i = 0; i < 4; ++i) {
      _Float16 h = (_Float16)acc[i];
      rh[i] = h;
      rl[i] = (_Float16)(acc[i] - (float)h);
    }
    int hpix = th * 8 + prow, wpix = tw * 32 + pcol;
    size_t pxbase = ((size_t)b * HW + hpix * 512 + wpix) * 64;
#pragma unroll
    for (int rt = 0; rt < 3; ++rt) {
      f32x4 a;
#pragma unroll
      for (int r = 0; r < 4; ++r) a[r] = sBq[rt * 16 + 4 * lg + r];
      a = __builtin_amdgcn_mfma_f32_16x16x16f16(WqH[rt], rh, a, 0, 0, 0);
      a = __builtin_amdgcn_mfma_f32_16x16x16f16(WqH[rt], rl, a, 0, 0, 0);
      a = __builtin_amdgcn_mfma_f32_16x16x16f16(WqL[rt], rh, a, 0, 0, 0);
      int ob = g * 48 + rt * 16 + 4 * lg;
      if (ob < 64) {
        *(float4*)(qn + pxbase + ob) = *(float4*)&a;
      } else if (ob < 128) {
        *(float4*)(kn + pxbase + (ob - 64)) = *(float4*)&a;
      } else {
        uint2 pk;
        pk.x = (uint32_t)f2h(a[0]) | ((uint32_t)f2h(a[1]) << 16);
        pk.y = (uint32_t)f2h(a[2]) | ((uint32_t)f2h(a[3]) << 16);
        *(uint2*)(vn + pxbase + (ob - 128)) = pk;
      }
    }
  }
}

// ---------------- fused per-window attention: split-fp16 MFMA, all-NHWC, XCD swizzle ----
__global__ __launch_bounds__(256, 4) void attn_k(
    const float* __restrict__ qLn, const float* __restrict__ qRn,  // NHWC fp32
    const float* __restrict__ kLn, const float* __restrict__ kRn,  // NHWC fp32
    const unsigned short* __restrict__ vLn, const unsigned short* __restrict__ vRn, // NHWC fp16
    const float* __restrict__ dL, const float* __restrict__ dR,
    const float* __restrict__ xL, const float* __restrict__ xR,
    float* outL, float* outR) {
  // XCD-aware swizzle: consecutive windows -> same XCD L2 (4096 % 8 == 0, bijective)
  const int orig = blockIdx.x;
  const int n = (orig & 7) * 512 + (orig >> 3);
  const int b = n >> 11, hb = (n >> 6) & 31, wb = n & 63;
  const int tid = threadIdx.x;
  const int lane = tid & 63, w = tid >> 6;
  const int l15 = lane & 15, lg = lane >> 4;

  // K hi/lo (stride KST=76 -> conflict-free QK^T reads) — reused as fp32 M (stride 68, msw)
  __shared__ __align__(16) unsigned short sK[4 * 64 * KST];  // 38912 B
  __shared__ float meanA[8], meanB[8], qsA[64], qsB[64], mapL[64], mapR[64];
  unsigned short* KHA = sK;
  unsigned short* KLA = sK + 64 * KST;
  unsigned short* KHB = sK + 2 * 64 * KST;
  unsigned short* KLB = sK + 3 * 64 * KST;
  float* M32A = (float*)sK;           // [64][68] msw layout (34816 B <= 38912 B)
  float* M32B = (float*)sK + 64 * 68; // [64][68]

  const float* dLb = dL + (size_t)b * HW;
  const float* dRb = dR + (size_t)b * HW;
  const size_t nb = (size_t)b * HW;

  // ---- K gather (NHWC): 2 iters, 8 channels per thread per dir ----
  const int cc0 = (wb & 7) * 8;
#pragma unroll
  for (int it = 0; it < 2; ++it) {
    int slot = tid + 256 * it;           // 0..511
    int c2 = slot & 63, k8 = slot >> 6;  // k8 0..7
    int hh = 4 * c2 + (hb >> 3);
    int ww = (hb & 7) * 64 + k8 * 8 + (wb >> 3);
    int dpos = hh * 512 + ww;
    int iwr = ww - (int)dLb[dpos]; iwr = min(max(iwr, 0), 511);
    int iwl = ww + (int)dRb[dpos]; iwl = min(max(iwl, 0), 511);
    const float* pr = kRn + (nb + hh * 512 + iwr) * 64 + cc0;
    const float* pl = kLn + (nb + hh * 512 + iwl) * 64 + cc0;
    float fr[8], fl[8];
    *(float4*)&fr[0] = *(const float4*)pr;
    *(float4*)&fr[4] = *(const float4*)(pr + 4);
    *(float4*)&fl[0] = *(const float4*)pl;
    *(float4*)&fl[4] = *(const float4*)(pl + 4);
#pragma unroll
    for (int kl = 0; kl < 8; ++kl) {
      int k = 8 * k8 + kl;
      unsigned short hr = f2h(fr[kl]), hl = f2h(fl[kl]);
      KHA[k * KST + c2] = hr; KLA[k * KST + c2] = f2h(fr[kl] - h2f(hr));
      KHB[k * KST + c2] = hl; KLB[k * KST + c2] = f2h(fl[kl] - h2f(hl));
    }
  }

  // ---- Q load (NHWC fp32) + hi/lo split ----
  const int jr = 16 * w + l15;
  const int hp = hb * 8 + (jr >> 3), wp = wb * 8 + (jr & 7);
  const int gpix = hp * 512 + wp;
  const float* qlp = qLn + (nb + gpix) * 64;
  const float* qrp = qRn + (nb + gpix) * 64;
  float qv0[8], qv1[8], qw0[8], qw1[8];
  *(float4*)&qv0[0] = *(const float4*)(qlp + 8 * lg);
  *(float4*)&qv0[4] = *(const float4*)(qlp + 8 * lg + 4);
  *(float4*)&qv1[0] = *(const float4*)(qlp + 32 + 8 * lg);
  *(float4*)&qv1[4] = *(const float4*)(qlp + 32 + 8 * lg + 4);
  *(float4*)&qw0[0] = *(const float4*)(qrp + 8 * lg);
  *(float4*)&qw0[4] = *(const float4*)(qrp + 8 * lg + 4);
  *(float4*)&qw1[0] = *(const float4*)(qrp + 32 + 8 * lg);
  *(float4*)&qw1[4] = *(const float4*)(qrp + 32 + 8 * lg + 4);
  f16x8 qah0, qal0, qah1, qal1, qbh0, qbl0, qbh1, qbl1;
#pragma unroll
  for (int e = 0; e < 8; ++e) {
    _Float16 h;
    h = (_Float16)qv0[e]; qah0[e] = h; qal0[e] = (_Float16)(qv0[e] - (float)h);
    h = (_Float16)qv1[e]; qah1[e] = h; qal1[e] = (_Float16)(qv1[e] - (float)h);
    h = (_Float16)qw0[e]; qbh0[e] = h; qbl0[e] = (_Float16)(qw0[e] - (float)h);
    h = (_Float16)qw1[e]; qbh1[e] = h; qbl1[e] = (_Float16)(qw1[e] - (float)h);
  }

  // ---- V fragments (NHWC fp16: one b128 per (h,dir)) ----
  int4 vAr[2], vBr[2];
  {
    const int cv = 16 * w + l15;
#pragma unroll
    for (int h = 0; h < 2; ++h) {
      int hi = 4 * h + lg;
      int hh = 4 * cv + (hb >> 3);
      int ww = (hb & 7) * 64 + hi * 8 + (wb >> 3);
      int dpos = hh * 512 + ww;
      int iwr = ww - (int)dLb[dpos]; iwr = min(max(iwr, 0), 511);
      int iwl = ww + (int)dRb[dpos]; iwl = min(max(iwl, 0), 511);
      vAr[h] = *(const int4*)(vRn + (nb + hh * 512 + iwr) * 64 + cc0);
      vBr[h] = *(const int4*)(vLn + (nb + hh * 512 + iwl) * 64 + cc0);
    }
  }
  __syncthreads();  // B1: K staged

  // ---- K means per (dir,hi) over (wi,c): exact = hi+lo ----
  {
    int grp = tid >> 4, i = tid & 15;
    int dir = grp >> 3, hi = grp & 7;
    int off0 = (8 * hi + (i >> 1)) * KST + (i & 1) * 32;
    const unsigned short* srcH = (dir ? KHB : KHA) + off0;
    const unsigned short* srcL = (dir ? KLB : KLA) + off0;
    float s = 0.f;
#pragma unroll
    for (int q = 0; q < 32; ++q) s += h2f(srcH[q]) + h2f(srcL[q]);
    for (int m = 8; m; m >>= 1) s += __shfl_xor(s, m, 64);
    if (i == 0) (dir ? meanB : meanA)[hi] = s * (1.f / 512.f);
  }
  // ---- qsum[j] (fp32 exact) ----
  {
    float sa = 0.f, sb = 0.f;
#pragma unroll
    for (int e = 0; e < 8; ++e) {
      sa += qv0[e] + qv1[e];
      sb += qw0[e] + qw1[e];
    }
    sa += __shfl_xor(sa, 16, 64); sa += __shfl_xor(sa, 32, 64);
    sb += __shfl_xor(sb, 16, 64); sb += __shfl_xor(sb, 32, 64);
    if (lane < 16) { qsA[jr] = sa; qsB[jr] = sb; }
  }
  __syncthreads();  // B2: means + qsums ready

  // ---- QK^T via split-fp16 MFMA: q.k ~= qh.kh + qh.kl + ql.kh ----
  f32x4 sA[4], sB[4];
#pragma unroll
  for (int t = 0; t < 4; ++t) { sA[t] = (f32x4){0.f, 0.f, 0.f, 0.f}; sB[t] = sA[t]; }
#pragma unroll
  for (int t = 0; t < 4; ++t) {
    int ro = (16 * t + l15) * KST + 8 * lg;
    f16x8 kh0 = *(const f16x8*)(KHA + ro);
    f16x8 kl0 = *(const f16x8*)(KLA + ro);
    f16x8 kh1 = *(const f16x8*)(KHA + ro + 32);
    f16x8 kl1 = *(const f16x8*)(KLA + ro + 32);
    sA[t] = __builtin_amdgcn_mfma_f32_16x16x32_f16(qah0, kh0, sA[t], 0, 0, 0);
    sA[t] = __builtin_amdgcn_mfma_f32_16x16x32_f16(qah0, kl0, sA[t], 0, 0, 0);
    sA[t] = __builtin_amdgcn_mfma_f32_16x16x32_f16(qal0, kh0, sA[t], 0, 0, 0);
    sA[t] = __builtin_amdgcn_mfma_f32_16x16x32_f16(qah1, kh1, sA[t], 0, 0, 0);
    sA[t] = __builtin_amdgcn_mfma_f32_16x16x32_f16(qah1, kl1, sA[t], 0, 0, 0);
    sA[t] = __builtin_amdgcn_mfma_f32_16x16x32_f16(qal1, kh1, sA[t], 0, 0, 0);
    f16x8 mh0 = *(const f16x8*)(KHB + ro);
    f16x8 ml0 = *(const f16x8*)(KLB + ro);
    f16x8 mh1 = *(const f16x8*)(KHB + ro + 32);
    f16x8 ml1 = *(const f16x8*)(KLB + ro + 32);
    sB[t] = __builtin_amdgcn_mfma_f32_16x16x32_f16(qbh0, mh0, sB[t], 0, 0, 0);
    sB[t] = __builtin_amdgcn_mfma_f32_16x16x32_f16(qbh0, ml0, sB[t], 0, 0, 0);
    sB[t] = __builtin_amdgcn_mfma_f32_16x16x32_f16(qbl0, mh0, sB[t], 0, 0, 0);
    sB[t] = __builtin_amdgcn_mfma_f32_16x16x32_f16(qbh1, mh1, sB[t], 0, 0, 0);
    sB[t] = __builtin_amdgcn_mfma_f32_16x16x32_f16(qbh1, ml1, sB[t], 0, 0, 0);
    sB[t] = __builtin_amdgcn_mfma_f32_16x16x32_f16(qbl1, mh1, sB[t], 0, 0, 0);
  }
  // ---- mean-fold correction + in-register softmax over k ----
  {
    float qra[4], qrb2[4];
#pragma unroll
    for (int reg = 0; reg < 4; ++reg) {
      qra[reg] = qsA[16 * w + 4 * lg + reg];
      qrb2[reg] = qsB[16 * w + 4 * lg + reg];
    }
#pragma unroll
    for (int t = 0; t < 4; ++t) {
      float mA_ = meanA[2 * t + (l15 >> 3)];
      float mB_ = meanB[2 * t + (l15 >> 3)];
#pragma unroll
      for (int reg = 0; reg < 4; ++reg) {
        sA[t][reg] -= qra[reg] * mA_;
        sB[t][reg] -= qrb2[reg] * mB_;
      }
    }
#pragma unroll
    for (int reg = 0; reg < 4; ++reg) {
      float ma = sA[0][reg], mb = sB[0][reg];
#pragma unroll
      for (int t = 1; t < 4; ++t) { ma = fmaxf(ma, sA[t][reg]); mb = fmaxf(mb, sB[t][reg]); }
#pragma unroll
      for (int m = 1; m <= 8; m <<= 1) {
        ma = fmaxf(ma, __shfl_xor(ma, m, 64));
        mb = fmaxf(mb, __shfl_xor(mb, m, 64));
      }
      float sa = 0.f, sb = 0.f;
#pragma unroll
      for (int t = 0; t < 4; ++t) {
        float ea = __expf(sA[t][reg] - ma), eb = __expf(sB[t][reg] - mb);
        sA[t][reg] = ea; sB[t][reg] = eb;
        sa += ea; sb += eb;
      }
#pragma unroll
      for (int m = 1; m <= 8; m <<= 1) {
        sa += __shfl_xor(sa, m, 64);
        sb += __shfl_xor(sb, m, 64);
      }
      float ra = 1.f / sa, rb = 1.f / sb;
#pragma unroll
      for (int t = 0; t < 4; ++t) { sA[t][reg] *= ra; sB[t][reg] *= rb; }
    }
  }
  __syncthreads();  // B2.5: all K reads done; overlay M32 onto K region

  // ---- write M fp32 (msw swizzle; serves both PV and m-map path) ----
#pragma unroll
  for (int t = 0; t < 4; ++t)
#pragma unroll
    for (int reg = 0; reg < 4; ++reg) {
      int jrow = 16 * w + 4 * lg + reg, kcol = 16 * t + l15;
      M32A[msw(jrow, kcol)] = sA[t][reg];
      M32B[msw(jrow, kcol)] = sB[t][reg];
    }
  __syncthreads();  // B3: M complete

  // ---- PV via MFMA (fp16 cvt from fp32 M): X^T[c][j] = sum_k V_sel[k][c] * M[j][k] ----
  f32x4 pL[4], pR[4];
#pragma unroll
  for (int t = 0; t < 4; ++t) { pL[t] = (f32x4){0.f, 0.f, 0.f, 0.f}; pR[t] = pL[t]; }
#pragma unroll
  for (int h = 0; h < 2; ++h) {
    f16x8 va = __builtin_bit_cast(f16x8, vAr[h]);
    f16x8 vb = __builtin_bit_cast(f16x8, vBr[h]);
#pragma unroll
    for (int jt = 0; jt < 4; ++jt) {
      const float* mra = M32A + msw(16 * jt + l15, 32 * h + 8 * lg);
      const float* mrb = M32B + msw(16 * jt + l15, 32 * h + 8 * lg);
      float fa[8], fb[8];
      *(float4*)&fa[0] = *(const float4*)mra;
      *(float4*)&fa[4] = *(const float4*)(mra + 4);
      *(float4*)&fb[0] = *(const float4*)mrb;
      *(float4*)&fb[4] = *(const float4*)(mrb + 4);
      f16x8 ma, mb;
#pragma unroll
      for (int e = 0; e < 8; ++e) { ma[e] = (_Float16)fa[e]; mb[e] = (_Float16)fb[e]; }
      pL[jt] = __builtin_amdgcn_mfma_f32_16x16x32_f16(va, ma, pL[jt], 0, 0, 0);
      pR[jt] = __builtin_amdgcn_mfma_f32_16x16x32_f16(vb, mb, pR[jt], 0, 0, 0);
    }
  }
  // ---- x blend prefetch (T14): issue loads before m_relax, use after B4 ----
  float xlv[4][4], xrv[4][4];
#pragma unroll
  for (int jt = 0; jt < 4; ++jt)
#pragma unroll
    for (int reg = 0; reg < 4; ++reg) {
      int c = 16 * w + 4 * lg + reg;
      int j = 16 * jt + l15;
      int hp2 = hb * 8 + (j >> 3), wp2 = wb * 8 + (j & 7);
      size_t off = ((size_t)(b * 64 + c)) * HW + hp2 * 512 + wp2;
      xlv[jt][reg] = xL[off];
      xrv[jt][reg] = xR[off];
    }
  // ---- m_relax band + einsum + tanh from fp32 M (128 threads) ----
  if (tid < 128) {
    int dir = tid >> 6, j = tid & 63;
    const float* Mrow = dir ? M32B : M32A;
    const float* Mcol = dir ? M32A : M32B;
    float acc = 0.f;
    for (int k = 0; k < 64; ++k) {
      float rx = 0.f;
#pragma unroll
      for (int i = -2; i <= 2; ++i) {
        int jj = j + i;
        if ((unsigned)jj < 64u) rx += Mrow[msw(jj, k)];
      }
      acc += rx * Mcol[msw(k, j)];
    }
    (dir ? mapR : mapL)[j] = tanhf(5.f * acc);
  }
  __syncthreads();  // B4: maps ready

  // ---- blend + store ----
#pragma unroll
  for (int jt = 0; jt < 4; ++jt) {
#pragma unroll
    for (int reg = 0; reg < 4; ++reg) {
      int c = 16 * w + 4 * lg + reg;
      int j = 16 * jt + l15;
      int hp2 = hb * 8 + (j >> 3), wp2 = wb * 8 + (j & 7);
      size_t off = ((size_t)(b * 64 + c)) * HW + hp2 * 512 + wp2;
      float ml = mapL[j], mr = mapR[j];
      outL[off] = xlv[jt][reg] * (1.f - ml) + pL[jt][reg] * ml;
      outR[off] = xrv[jt][reg] * (1.f - mr) + pR[jt][reg] * mr;
    }
  }
}

extern "C" void kernel_launch(void* const* d_in, const int* in_sizes, int n_in,
                              void* d_out, int out_size, void* d_ws, size_t ws_size,
                              hipStream_t stream) {
  const float* x_left = (const float*)d_in[0];
  const float* x_right = (const float*)d_in[1];
  const float* d_left = (const float*)d_in[2];
  const float* d_right = (const float*)d_in[3];
  const float* bn_gamma = (const float*)d_in[4];
  const float* bn_beta = (const float*)d_in[5];
  const float* rb_w1 = (const float*)d_in[6];
  const float* rb_b1 = (const float*)d_in[7];
  const float* rb_w2 = (const float*)d_in[8];
  const float* rb_b2 = (const float*)d_in[9];
  const float* qkv_w = (const float*)d_in[10];
  const float* qkv_b = (const float*)d_in[11];

  float* ws = (float*)d_ws;
  const size_t S = S_ELEMS;
  unsigned short* tL = (unsigned short*)ws;              // S ushorts (conv1 out fp16)
  unsigned short* tR = tL + S;                           // S ushorts (ends at ws+S floats)
  float* knL = ws + 2 * S;           // S floats NHWC [b*HW+p][64]
  float* knR = ws + 3 * S;           // S floats
  unsigned short* vnL = (unsigned short*)(ws + 4 * S);   // S ushorts NHWC
  unsigned short* vnR = vnL + S;                         // S ushorts
  float* qnL = ws + 5 * S;           // S floats NHWC
  float* qnR = ws + 6 * S;           // S floats

  // partial/stats at head of d_out: written by bn kernels, read by conv kernels,
  // overwritten by attn's blend at the end (stream order guarantees safety).
  float* out_left = (float*)d_out;
  float* out_right = out_left + S;
  float2* partial = (float2*)d_out;              // 2048 float2
  float* stats = (float*)d_out + 4096;           // 256 floats

  bn_part_k<<<2048, 256, 0, stream>>>(x_left, x_right, partial);
  bn_fin_k<<<1, 128, 0, stream>>>(partial, bn_gamma, bn_beta, stats);

  conv1_k<<<8192, 256, 0, stream>>>(x_left, x_right, rb_w1, rb_b1, stats, tL, tR);
  conv2_qkv_k<<<8192, 256, 0, stream>>>(tL, tR, x_left, x_right, rb_w2, rb_b2,
                                        qkv_w, qkv_b, stats,
                                        qnL, qnR, knL, knR, vnL, vnR);
  attn_k<<<4096, 256, 0, stream>>>(qnL, qnR, knL, knR, vnL, vnR,
                                   d_left, d_right, x_left, x_right,
                                   out_left, out_right);
}

// Round 22
// 621.008 us; speedup vs baseline: 1.0092x; 1.0092x over previous
//
#include <hip/hip_runtime.h>
#include <cstdint>

#define HW 131072        // H*W
#define S_ELEMS 16777216 // B*C*H*W

typedef __attribute__((ext_vector_type(8))) _Float16 f16x8;
typedef __attribute__((ext_vector_type(4))) _Float16 f16x4;
typedef __attribute__((ext_vector_type(4))) float f32x4;

__device__ __forceinline__ float h2f(unsigned short u) {
  return (float)__builtin_bit_cast(_Float16, u);
}
__device__ __forceinline__ unsigned short f2h(float f) {
  return __builtin_bit_cast(unsigned short, (_Float16)f);
}
// M32 bank swizzle: XOR col 8-blocks by row-class; kills j/j+8/j+16/j+24 bank aliasing
// while keeping 8-float blocks contiguous (float4-aligned reads still valid).
__device__ __forceinline__ int msw(int r, int c) {
  return r * 68 + (c ^ (((r >> 3) & 3) << 3));
}
// attn K-tile row stride (ushorts). 76 experiment regressed (round 21); reverted to 72.
#define KST 72

// ---------------- BN stats stage 1: partial sums (2 sides x 64 c x 16 slabs) ----------------
__global__ __launch_bounds__(256) void bn_part_k(const float* __restrict__ xL,
                                                 const float* __restrict__ xR,
                                                 float2* __restrict__ partial) {
  int bid = blockIdx.x;
  int side = bid >> 10, rest = bid & 1023;
  int c = rest >> 4, sl = rest & 15;
  const float* x = side ? xR : xL;
  const float4* p = (const float4*)(x + ((size_t)((sl >> 3) * 64 + c)) * HW + (size_t)(sl & 7) * 16384);
  float s1 = 0.f, s2 = 0.f;
  for (int i = threadIdx.x; i < 4096; i += 256) {
    float4 v = p[i];
    s1 += v.x + v.y + v.z + v.w;
    s2 += v.x * v.x + v.y * v.y + v.z * v.z + v.w * v.w;
  }
  for (int m = 32; m; m >>= 1) {
    s1 += __shfl_xor(s1, m, 64);
    s2 += __shfl_xor(s2, m, 64);
  }
  __shared__ float r1[4], r2[4];
  int wv = threadIdx.x >> 6;
  if ((threadIdx.x & 63) == 0) { r1[wv] = s1; r2[wv] = s2; }
  __syncthreads();
  if (threadIdx.x == 0) {
    partial[bid] = make_float2(r1[0] + r1[1] + r1[2] + r1[3], r2[0] + r2[1] + r2[2] + r2[3]);
  }
}

// ---------------- BN stats stage 2: finalize scale/shift ----------------
__global__ __launch_bounds__(128) void bn_fin_k(const float2* __restrict__ partial,
                                                const float* __restrict__ gamma,
                                                const float* __restrict__ beta,
                                                float* __restrict__ stats) {
  int tid = threadIdx.x;  // 0..127: side*64 + c
  int side = tid >> 6, c = tid & 63;
  float s1 = 0.f, s2 = 0.f;
  const float2* p = partial + (side * 1024 + c * 16);
  for (int s = 0; s < 16; ++s) { float2 v = p[s]; s1 += v.x; s2 += v.y; }
  float mu = s1 / 262144.f;
  float var = s2 / 262144.f - mu * mu;
  float rs = rsqrtf(var + 1e-5f);
  float sc = rs * gamma[c];
  stats[side * 128 + c] = sc;
  stats[side * 128 + 64 + c] = beta[c] - mu * sc;
}

// ---------------- conv1 via MFMA implicit GEMM: bn(x) fp16 -> 9-tap MFMA -> leaky -> t fp16 --
__global__ __launch_bounds__(256) void conv1_k(const float* __restrict__ xL,
                                               const float* __restrict__ xR,
                                               const float* __restrict__ wgt,
                                               const float* __restrict__ bias,
                                               const float* __restrict__ stats,
                                               unsigned short* __restrict__ tL,
                                               unsigned short* __restrict__ tR) {
  // ci-stride 372 ushorts -> fragment reads bank-spread (same as conv2)
  __shared__ __align__(16) unsigned short sInH[16 * 372];
  __shared__ __align__(16) float sW1r[2304];  // raw w1 [o][ci][9]
  __shared__ float sB1[16], sSc[16], sSh[16];
  int bid = blockIdx.x;
  int side = bid >> 12, rest = bid & 4095;
  int tw = rest & 15, th = (rest >> 4) & 31, g = (rest >> 9) & 3, b = rest >> 11;
  const float* in = side ? xR : xL;
  unsigned short* out = side ? tR : tL;
  const float* ss = stats + side * 128;
  int tid = threadIdx.x;
  const int lane = tid & 63, wv = tid >> 6;
  const int l15 = lane & 15, lg = lane >> 4;

  for (int e = tid; e < 2304; e += 256) sW1r[e] = wgt[g * 2304 + e];
  if (tid < 16) {
    sB1[tid] = bias[g * 16 + tid];
    sSc[tid] = ss[g * 16 + tid];
    sSh[tid] = ss[64 + g * 16 + tid];
  }
  __syncthreads();  // RACE FIX: sSc/sSh visible before staging reads them
  int h0 = th * 8 - 1, w0 = tw * 32 - 1;
  const float* inb = in + ((size_t)(b * 64 + g * 16)) * HW;
  for (int e = tid; e < 5440; e += 256) {
    int ci = e / 340, rem = e - ci * 340, r = rem / 34, c = rem - r * 34;
    int h = h0 + r, w = w0 + c;
    unsigned short v = 0;
    if ((unsigned)h < 256u && (unsigned)w < 512u) {
      v = f2h(inb[(size_t)ci * HW + h * 512 + w] * sSc[ci] + sSh[ci]);
    }
    sInH[ci * 372 + r * 36 + c] = v;
  }
  __syncthreads();

  // hoist W1 tap fragments (hi/lo): A-frag lane holds W[oc=l15][ci=4lg+i]
  f16x4 W1H[9], W1L[9];
#pragma unroll
  for (int tap = 0; tap < 9; ++tap) {
#pragma unroll
    for (int i = 0; i < 4; ++i) {
      float f = sW1r[l15 * 144 + (4 * lg + i) * 9 + tap];
      _Float16 h = (_Float16)f;
      W1H[tap][i] = h;
      W1L[tap][i] = (_Float16)(f - (float)h);
    }
  }
  float b14[4];
#pragma unroll
  for (int r = 0; r < 4; ++r) b14[r] = sB1[4 * lg + r];

  // per 16-px column block: 9-tap MFMA -> leaky -> f2h -> planar store
#pragma unroll
  for (int j = 0; j < 4; ++j) {
    int ct = 4 * wv + j;
    int px = ct * 16 + l15;
    int prow = px >> 5, pcol = px & 31;
    const unsigned short* p0 = sInH + (4 * lg) * 372 + prow * 36 + pcol;
    f32x4 acc;
#pragma unroll
    for (int r = 0; r < 4; ++r) acc[r] = b14[r];
#pragma unroll
    for (int kh = 0; kh < 3; ++kh) {
#pragma unroll
      for (int kw = 0; kw < 3; ++kw) {
        int toff = kh * 36 + kw;
        f16x4 it;
#pragma unroll
        for (int i = 0; i < 4; ++i)
          it[i] = __builtin_bit_cast(_Float16, p0[i * 372 + toff]);
        acc = __builtin_amdgcn_mfma_f32_16x16x16f16(W1H[kh * 3 + kw], it, acc, 0, 0, 0);
        acc = __builtin_amdgcn_mfma_f32_16x16x16f16(W1L[kh * 3 + kw], it, acc, 0, 0, 0);
      }
    }
    int hpix = th * 8 + prow, wpix = tw * 32 + pcol;
    size_t rowoff = (size_t)hpix * 512 + wpix;
#pragma unroll
    for (int r = 0; r < 4; ++r) {
      float a = acc[r];
      a = a > 0.f ? a : 0.1f * a;
      out[((size_t)(b * 64 + g * 16 + 4 * lg + r)) * HW + rowoff] = f2h(a);
    }
  }
}

// ---------------- fused conv2(MFMA implicit GEMM) + residual + qkv(MFMA); both sides --------
__global__ __launch_bounds__(256) void conv2_qkv_k(
    const unsigned short* __restrict__ tL, const unsigned short* __restrict__ tR,
    const float* __restrict__ xL, const float* __restrict__ xR,
    const float* __restrict__ w2g, const float* __restrict__ b2g,
    const float* __restrict__ wq, const float* __restrict__ bq,
    const float* __restrict__ stats,
    float* __restrict__ qnL, float* __restrict__ qnR,
    float* __restrict__ knL, float* __restrict__ knR,
    unsigned short* __restrict__ vnL, unsigned short* __restrict__ vnR) {
  __shared__ __align__(16) unsigned short sInH[16 * 372];  // conv1-out fp16 tile +1 halo
  __shared__ __align__(16) float sW2r[2304];               // raw w2 [o][ci][9]
  __shared__ __align__(16) float sWq[768];
  __shared__ float sB2[16], sBq[48], sSc[16], sSh[16];

  int bid = blockIdx.x;
  int side = bid >> 12, rest = bid & 4095;
  int tw = rest & 15, th = (rest >> 4) & 31, g = (rest >> 9) & 3, b = rest >> 11;
  const unsigned short* t = side ? tR : tL;
  const float* x = side ? xR : xL;
  float* qn = side ? qnR : qnL;
  float* kn = side ? knR : knL;
  unsigned short* vn = side ? vnR : vnL;
  const float* ss = stats + side * 128;
  int tid = threadIdx.x;
  const int lane = tid & 63, wv = tid >> 6;
  const int l15 = lane & 15, lg = lane >> 4;

  // early residual prefetch (T14), in D layout: oc=4lg+r, px=ct*16+l15
  float resx[4][4];
#pragma unroll
  for (int j = 0; j < 4; ++j) {
    int px = (4 * wv + j) * 16 + l15;
    int hpix = th * 8 + (px >> 5), wpix = tw * 32 + (px & 31);
    size_t rowoff = (size_t)hpix * 512 + wpix;
#pragma unroll
    for (int r = 0; r < 4; ++r)
      resx[j][r] = x[((size_t)(b * 64 + g * 16 + 4 * lg + r)) * HW + rowoff];
  }

  // stage weights / biases / bn scale-shift
  for (int e = tid; e < 2304; e += 256) sW2r[e] = w2g[g * 2304 + e];
  for (int e = tid; e < 768; e += 256) {
    int oo = e >> 4, ci = e & 15;
    sWq[e] = wq[(g * 48 + oo) * 16 + ci];
  }
  if (tid < 48) sBq[tid] = bq[g * 48 + tid];
  if (tid < 16) {
    sB2[tid] = b2g[g * 16 + tid];
    sSc[tid] = ss[g * 16 + tid];
    sSh[tid] = ss[64 + g * 16 + tid];
  }

  // stage conv1-out tile (1-halo) from global fp16 -> LDS fp16 (padded stride)
  int h0 = th * 8 - 1, w0 = tw * 32 - 1;
  const unsigned short* inb = t + ((size_t)(b * 64 + g * 16)) * HW;
  for (int e = tid; e < 5440; e += 256) {
    int ci = e / 340, rem = e - ci * 340, r = rem / 34, c = rem - r * 34;
    int h = h0 + r, w = w0 + c;
    unsigned short v = 0;
    if ((unsigned)h < 256u && (unsigned)w < 512u) {
      v = inb[(size_t)ci * HW + h * 512 + w];
    }
    sInH[ci * 372 + r * 36 + c] = v;
  }
  __syncthreads();  // weights + tile staged (single barrier; nothing else writes LDS)

  // hoist A fragments: W2 taps (hi/lo split) + Wq (hi/lo)
  f16x4 W2H[9], W2L[9];
#pragma unroll
  for (int tap = 0; tap < 9; ++tap) {
#pragma unroll
    for (int i = 0; i < 4; ++i) {
      float f = sW2r[l15 * 144 + (4 * lg + i) * 9 + tap];
      _Float16 h = (_Float16)f;
      W2H[tap][i] = h;
      W2L[tap][i] = (_Float16)(f - (float)h);
    }
  }
  f16x4 WqH[3], WqL[3];
#pragma unroll
  for (int rt = 0; rt < 3; ++rt) {
    float4 wvv = *(const float4*)(sWq + (rt * 16 + l15) * 16 + 4 * lg);
#pragma unroll
    for (int i = 0; i < 4; ++i) {
      float f = ((float*)&wvv)[i];
      _Float16 h = (_Float16)f;
      WqH[rt][i] = h;
      WqL[rt][i] = (_Float16)(f - (float)h);
    }
  }
  float sc4[4], sh4[4], b24[4];
#pragma unroll
  for (int r = 0; r < 4; ++r) {
    sc4[r] = sSc[4 * lg + r];
    sh4[r] = sSh[4 * lg + r];
    b24[r] = sB2[4 * lg + r];
  }

  // per 16-px column block: conv2 MFMA -> residual -> split -> qkv MFMA -> store
#pragma unroll
  for (int j = 0; j < 4; ++j) {
    int ct = 4 * wv + j;
    int px = ct * 16 + l15;
    int prow = px >> 5, pcol = px & 31;
    const unsigned short* p0 = sInH + (4 * lg) * 372 + prow * 36 + pcol;
    f32x4 acc;
#pragma unroll
    for (int r = 0; r < 4; ++r) acc[r] = b24[r];
#pragma unroll
    for (int kh = 0; kh < 3; ++kh) {
#pragma unroll
      for (int kw = 0; kw < 3; ++kw) {
        int toff = kh * 36 + kw;
        f16x4 it;
#pragma unroll
        for (int i = 0; i < 4; ++i)
          it[i] = __builtin_bit_cast(_Float16, p0[i * 372 + toff]);
        acc = __builtin_amdgcn_mfma_f32_16x16x16f16(W2H[kh * 3 + kw], it, acc, 0, 0, 0);
        acc = __builtin_amdgcn_mfma_f32_16x16x16f16(W2L[kh * 3 + kw], it, acc, 0, 0, 0);
      }
    }
#pragma unroll
    for (int r = 0; r < 4; ++r) acc[r] += resx[j][r] * sc4[r] + sh4[r];
    // split r fragment (conv2 D == qkv B mapping: lane holds ci=4lg+i at px)
    f16x4 rh, rl;
#pragma unroll
    for (int i = 0; i < 4; ++i) {
      _Float16 h = (_Float16)acc[i];
      rh[i] = h;
      rl[i] = (_Float16)(acc[i] - (float)h);
    }
    int hpix = th * 8 + prow, wpix = tw * 32 + pcol;
    size_t pxbase = ((size_t)b * HW + hpix * 512 + wpix) * 64;
#pragma unroll
    for (int rt = 0; rt < 3; ++rt) {
      f32x4 a;
#pragma unroll
      for (int r = 0; r < 4; ++r) a[r] = sBq[rt * 16 + 4 * lg + r];
      a = __builtin_amdgcn_mfma_f32_16x16x16f16(WqH[rt], rh, a, 0, 0, 0);
      a = __builtin_amdgcn_mfma_f32_16x16x16f16(WqH[rt], rl, a, 0, 0, 0);
      a = __builtin_amdgcn_mfma_f32_16x16x16f16(WqL[rt], rh, a, 0, 0, 0);
      int ob = g * 48 + rt * 16 + 4 * lg;
      if (ob < 64) {
        *(float4*)(qn + pxbase + ob) = *(float4*)&a;
      } else if (ob < 128) {
        *(float4*)(kn + pxbase + (ob - 64)) = *(float4*)&a;
      } else {
        uint2 pk;
        pk.x = (uint32_t)f2h(a[0]) | ((uint32_t)f2h(a[1]) << 16);
        pk.y = (uint32_t)f2h(a[2]) | ((uint32_t)f2h(a[3]) << 16);
        *(uint2*)(vn + pxbase + (ob - 128)) = pk;
      }
    }
  }
}

// ---------------- fused per-window attention: split-fp16 MFMA, all-NHWC, XCD swizzle ----
__global__ __launch_bounds__(256, 4) void attn_k(
    const float* __restrict__ qLn, const float* __restrict__ qRn,  // NHWC fp32
    const float* __restrict__ kLn, const float* __restrict__ kRn,  // NHWC fp32
    const unsigned short* __restrict__ vLn, const unsigned short* __restrict__ vRn, // NHWC fp16
    const float* __restrict__ dL, const float* __restrict__ dR,
    const float* __restrict__ xL, const float* __restrict__ xR,
    float* outL, float* outR) {
  // XCD-aware swizzle: consecutive windows -> same XCD L2 (4096 % 8 == 0, bijective)
  const int orig = blockIdx.x;
  const int n = (orig & 7) * 512 + (orig >> 3);
  const int b = n >> 11, hb = (n >> 6) & 31, wb = n & 63;
  const int tid = threadIdx.x;
  const int lane = tid & 63, w = tid >> 6;
  const int l15 = lane & 15, lg = lane >> 4;

  // K hi/lo (stride KST=72, fp16) — reused after QK^T as fp32 M (stride 68, msw)
  __shared__ __align__(16) unsigned short sK[4 * 64 * KST];  // 36864 B
  __shared__ float meanA[8], meanB[8], qsA[64], qsB[64], mapL[64], mapR[64];
  unsigned short* KHA = sK;
  unsigned short* KLA = sK + 64 * KST;
  unsigned short* KHB = sK + 2 * 64 * KST;
  unsigned short* KLB = sK + 3 * 64 * KST;
  float* M32A = (float*)sK;           // [64][68] msw layout
  float* M32B = (float*)sK + 64 * 68; // [64][68]

  const float* dLb = dL + (size_t)b * HW;
  const float* dRb = dR + (size_t)b * HW;
  const size_t nb = (size_t)b * HW;

  // ---- K gather (NHWC): 2 iters, 8 channels per thread per dir ----
  const int cc0 = (wb & 7) * 8;
#pragma unroll
  for (int it = 0; it < 2; ++it) {
    int slot = tid + 256 * it;           // 0..511
    int c2 = slot & 63, k8 = slot >> 6;  // k8 0..7
    int hh = 4 * c2 + (hb >> 3);
    int ww = (hb & 7) * 64 + k8 * 8 + (wb >> 3);
    int dpos = hh * 512 + ww;
    int iwr = ww - (int)dLb[dpos]; iwr = min(max(iwr, 0), 511);
    int iwl = ww + (int)dRb[dpos]; iwl = min(max(iwl, 0), 511);
    const float* pr = kRn + (nb + hh * 512 + iwr) * 64 + cc0;
    const float* pl = kLn + (nb + hh * 512 + iwl) * 64 + cc0;
    float fr[8], fl[8];
    *(float4*)&fr[0] = *(const float4*)pr;
    *(float4*)&fr[4] = *(const float4*)(pr + 4);
    *(float4*)&fl[0] = *(const float4*)pl;
    *(float4*)&fl[4] = *(const float4*)(pl + 4);
#pragma unroll
    for (int kl = 0; kl < 8; ++kl) {
      int k = 8 * k8 + kl;
      unsigned short hr = f2h(fr[kl]), hl = f2h(fl[kl]);
      KHA[k * KST + c2] = hr; KLA[k * KST + c2] = f2h(fr[kl] - h2f(hr));
      KHB[k * KST + c2] = hl; KLB[k * KST + c2] = f2h(fl[kl] - h2f(hl));
    }
  }

  // ---- Q load (NHWC fp32) + hi/lo split ----
  const int jr = 16 * w + l15;
  const int hp = hb * 8 + (jr >> 3), wp = wb * 8 + (jr & 7);
  const int gpix = hp * 512 + wp;
  const float* qlp = qLn + (nb + gpix) * 64;
  const float* qrp = qRn + (nb + gpix) * 64;
  float qv0[8], qv1[8], qw0[8], qw1[8];
  *(float4*)&qv0[0] = *(const float4*)(qlp + 8 * lg);
  *(float4*)&qv0[4] = *(const float4*)(qlp + 8 * lg + 4);
  *(float4*)&qv1[0] = *(const float4*)(qlp + 32 + 8 * lg);
  *(float4*)&qv1[4] = *(const float4*)(qlp + 32 + 8 * lg + 4);
  *(float4*)&qw0[0] = *(const float4*)(qrp + 8 * lg);
  *(float4*)&qw0[4] = *(const float4*)(qrp + 8 * lg + 4);
  *(float4*)&qw1[0] = *(const float4*)(qrp + 32 + 8 * lg);
  *(float4*)&qw1[4] = *(const float4*)(qrp + 32 + 8 * lg + 4);
  f16x8 qah0, qal0, qah1, qal1, qbh0, qbl0, qbh1, qbl1;
#pragma unroll
  for (int e = 0; e < 8; ++e) {
    _Float16 h;
    h = (_Float16)qv0[e]; qah0[e] = h; qal0[e] = (_Float16)(qv0[e] - (float)h);
    h = (_Float16)qv1[e]; qah1[e] = h; qal1[e] = (_Float16)(qv1[e] - (float)h);
    h = (_Float16)qw0[e]; qbh0[e] = h; qbl0[e] = (_Float16)(qw0[e] - (float)h);
    h = (_Float16)qw1[e]; qbh1[e] = h; qbl1[e] = (_Float16)(qw1[e] - (float)h);
  }

  // ---- V fragments (NHWC fp16: one b128 per (h,dir)) ----
  int4 vAr[2], vBr[2];
  {
    const int cv = 16 * w + l15;
#pragma unroll
    for (int h = 0; h < 2; ++h) {
      int hi = 4 * h + lg;
      int hh = 4 * cv + (hb >> 3);
      int ww = (hb & 7) * 64 + hi * 8 + (wb >> 3);
      int dpos = hh * 512 + ww;
      int iwr = ww - (int)dLb[dpos]; iwr = min(max(iwr, 0), 511);
      int iwl = ww + (int)dRb[dpos]; iwl = min(max(iwl, 0), 511);
      vAr[h] = *(const int4*)(vRn + (nb + hh * 512 + iwr) * 64 + cc0);
      vBr[h] = *(const int4*)(vLn + (nb + hh * 512 + iwl) * 64 + cc0);
    }
  }
  __syncthreads();  // B1: K staged

  // ---- K means per (dir,hi) over (wi,c): exact = hi+lo  (no barrier before QK^T:
  //      means/qsums are consumed only after B2, which now sits after the MFMA block) ----
  {
    int grp = tid >> 4, i = tid & 15;
    int dir = grp >> 3, hi = grp & 7;
    int off0 = (8 * hi + (i >> 1)) * KST + (i & 1) * 32;
    const unsigned short* srcH = (dir ? KHB : KHA) + off0;
    const unsigned short* srcL = (dir ? KLB : KLA) + off0;
    float s = 0.f;
#pragma unroll
    for (int q = 0; q < 32; ++q) s += h2f(srcH[q]) + h2f(srcL[q]);
    for (int m = 8; m; m >>= 1) s += __shfl_xor(s, m, 64);
    if (i == 0) (dir ? meanB : meanA)[hi] = s * (1.f / 512.f);
  }
  // ---- qsum[j] (fp32 exact) ----
  {
    float sa = 0.f, sb = 0.f;
#pragma unroll
    for (int e = 0; e < 8; ++e) {
      sa += qv0[e] + qv1[e];
      sb += qw0[e] + qw1[e];
    }
    sa += __shfl_xor(sa, 16, 64); sa += __shfl_xor(sa, 32, 64);
    sb += __shfl_xor(sb, 16, 64); sb += __shfl_xor(sb, 32, 64);
    if (lane < 16) { qsA[jr] = sa; qsB[jr] = sb; }
  }

  // ---- QK^T via split-fp16 MFMA: q.k ~= qh.kh + qh.kl + ql.kh ----
  f32x4 sA[4], sB[4];
#pragma unroll
  for (int t = 0; t < 4; ++t) { sA[t] = (f32x4){0.f, 0.f, 0.f, 0.f}; sB[t] = sA[t]; }
#pragma unroll
  for (int t = 0; t < 4; ++t) {
    int ro = (16 * t + l15) * KST + 8 * lg;
    f16x8 kh0 = *(const f16x8*)(KHA + ro);
    f16x8 kl0 = *(const f16x8*)(KLA + ro);
    f16x8 kh1 = *(const f16x8*)(KHA + ro + 32);
    f16x8 kl1 = *(const f16x8*)(KLA + ro + 32);
    sA[t] = __builtin_amdgcn_mfma_f32_16x16x32_f16(qah0, kh0, sA[t], 0, 0, 0);
    sA[t] = __builtin_amdgcn_mfma_f32_16x16x32_f16(qah0, kl0, sA[t], 0, 0, 0);
    sA[t] = __builtin_amdgcn_mfma_f32_16x16x32_f16(qal0, kh0, sA[t], 0, 0, 0);
    sA[t] = __builtin_amdgcn_mfma_f32_16x16x32_f16(qah1, kh1, sA[t], 0, 0, 0);
    sA[t] = __builtin_amdgcn_mfma_f32_16x16x32_f16(qah1, kl1, sA[t], 0, 0, 0);
    sA[t] = __builtin_amdgcn_mfma_f32_16x16x32_f16(qal1, kh1, sA[t], 0, 0, 0);
    f16x8 mh0 = *(const f16x8*)(KHB + ro);
    f16x8 ml0 = *(const f16x8*)(KLB + ro);
    f16x8 mh1 = *(const f16x8*)(KHB + ro + 32);
    f16x8 ml1 = *(const f16x8*)(KLB + ro + 32);
    sB[t] = __builtin_amdgcn_mfma_f32_16x16x32_f16(qbh0, mh0, sB[t], 0, 0, 0);
    sB[t] = __builtin_amdgcn_mfma_f32_16x16x32_f16(qbh0, ml0, sB[t], 0, 0, 0);
    sB[t] = __builtin_amdgcn_mfma_f32_16x16x32_f16(qbl0, mh0, sB[t], 0, 0, 0);
    sB[t] = __builtin_amdgcn_mfma_f32_16x16x32_f16(qbh1, mh1, sB[t], 0, 0, 0);
    sB[t] = __builtin_amdgcn_mfma_f32_16x16x32_f16(qbh1, ml1, sB[t], 0, 0, 0);
    sB[t] = __builtin_amdgcn_mfma_f32_16x16x32_f16(qbl1, mh1, sB[t], 0, 0, 0);
  }
  __syncthreads();  // B2 (moved): means + qsums now guaranteed visible

  // ---- mean-fold correction + in-register softmax over k ----
  {
    float qra[4], qrb2[4];
#pragma unroll
    for (int reg = 0; reg < 4; ++reg) {
      qra[reg] = qsA[16 * w + 4 * lg + reg];
      qrb2[reg] = qsB[16 * w + 4 * lg + reg];
    }
#pragma unroll
    for (int t = 0; t < 4; ++t) {
      float mA_ = meanA[2 * t + (l15 >> 3)];
      float mB_ = meanB[2 * t + (l15 >> 3)];
#pragma unroll
      for (int reg = 0; reg < 4; ++reg) {
        sA[t][reg] -= qra[reg] * mA_;
        sB[t][reg] -= qrb2[reg] * mB_;
      }
    }
#pragma unroll
    for (int reg = 0; reg < 4; ++reg) {
      float ma = sA[0][reg], mb = sB[0][reg];
#pragma unroll
      for (int t = 1; t < 4; ++t) { ma = fmaxf(ma, sA[t][reg]); mb = fmaxf(mb, sB[t][reg]); }
#pragma unroll
      for (int m = 1; m <= 8; m <<= 1) {
        ma = fmaxf(ma, __shfl_xor(ma, m, 64));
        mb = fmaxf(mb, __shfl_xor(mb, m, 64));
      }
      float sa = 0.f, sb = 0.f;
#pragma unroll
      for (int t = 0; t < 4; ++t) {
        float ea = __expf(sA[t][reg] - ma), eb = __expf(sB[t][reg] - mb);
        sA[t][reg] = ea; sB[t][reg] = eb;
        sa += ea; sb += eb;
      }
#pragma unroll
      for (int m = 1; m <= 8; m <<= 1) {
        sa += __shfl_xor(sa, m, 64);
        sb += __shfl_xor(sb, m, 64);
      }
      float ra = 1.f / sa, rb = 1.f / sb;
#pragma unroll
      for (int t = 0; t < 4; ++t) { sA[t][reg] *= ra; sB[t][reg] *= rb; }
    }
  }
  __syncthreads();  // B2.5: all K reads done; overlay M32 onto K region

  // ---- write M fp32 (msw swizzle; serves both PV and m-map path) ----
#pragma unroll
  for (int t = 0; t < 4; ++t)
#pragma unroll
    for (int reg = 0; reg < 4; ++reg) {
      int jrow = 16 * w + 4 * lg + reg, kcol = 16 * t + l15;
      M32A[msw(jrow, kcol)] = sA[t][reg];
      M32B[msw(jrow, kcol)] = sB[t][reg];
    }
  __syncthreads();  // B3: M complete

  // ---- PV via MFMA (fp16 cvt from fp32 M): X^T[c][j] = sum_k V_sel[k][c] * M[j][k] ----
  f32x4 pL[4], pR[4];
#pragma unroll
  for (int t = 0; t < 4; ++t) { pL[t] = (f32x4){0.f, 0.f, 0.f, 0.f}; pR[t] = pL[t]; }
#pragma unroll
  for (int h = 0; h < 2; ++h) {
    f16x8 va = __builtin_bit_cast(f16x8, vAr[h]);
    f16x8 vb = __builtin_bit_cast(f16x8, vBr[h]);
#pragma unroll
    for (int jt = 0; jt < 4; ++jt) {
      const float* mra = M32A + msw(16 * jt + l15, 32 * h + 8 * lg);
      const float* mrb = M32B + msw(16 * jt + l15, 32 * h + 8 * lg);
      float fa[8], fb[8];
      *(float4*)&fa[0] = *(const float4*)mra;
      *(float4*)&fa[4] = *(const float4*)(mra + 4);
      *(float4*)&fb[0] = *(const float4*)mrb;
      *(float4*)&fb[4] = *(const float4*)(mrb + 4);
      f16x8 ma, mb;
#pragma unroll
      for (int e = 0; e < 8; ++e) { ma[e] = (_Float16)fa[e]; mb[e] = (_Float16)fb[e]; }
      pL[jt] = __builtin_amdgcn_mfma_f32_16x16x32_f16(va, ma, pL[jt], 0, 0, 0);
      pR[jt] = __builtin_amdgcn_mfma_f32_16x16x32_f16(vb, mb, pR[jt], 0, 0, 0);
    }
  }
  // ---- x blend prefetch (T14): issue loads before m_relax, use after B4 ----
  float xlv[4][4], xrv[4][4];
#pragma unroll
  for (int jt = 0; jt < 4; ++jt)
#pragma unroll
    for (int reg = 0; reg < 4; ++reg) {
      int c = 16 * w + 4 * lg + reg;
      int j = 16 * jt + l15;
      int hp2 = hb * 8 + (j >> 3), wp2 = wb * 8 + (j & 7);
      size_t off = ((size_t)(b * 64 + c)) * HW + hp2 * 512 + wp2;
      xlv[jt][reg] = xL[off];
      xrv[jt][reg] = xR[off];
    }
  // ---- m_relax band + einsum + tanh from fp32 M (128 threads) ----
  if (tid < 128) {
    int dir = tid >> 6, j = tid & 63;
    const float* Mrow = dir ? M32B : M32A;
    const float* Mcol = dir ? M32A : M32B;
    float acc = 0.f;
    for (int k = 0; k < 64; ++k) {
      float rx = 0.f;
#pragma unroll
      for (int i = -2; i <= 2; ++i) {
        int jj = j + i;
        if ((unsigned)jj < 64u) rx += Mrow[msw(jj, k)];
      }
      acc += rx * Mcol[msw(k, j)];
    }
    (dir ? mapR : mapL)[j] = tanhf(5.f * acc);
  }
  __syncthreads();  // B4: maps ready

  // ---- blend + store ----
#pragma unroll
  for (int jt = 0; jt < 4; ++jt) {
#pragma unroll
    for (int reg = 0; reg < 4; ++reg) {
      int c = 16 * w + 4 * lg + reg;
      int j = 16 * jt + l15;
      int hp2 = hb * 8 + (j >> 3), wp2 = wb * 8 + (j & 7);
      size_t off = ((size_t)(b * 64 + c)) * HW + hp2 * 512 + wp2;
      float ml = mapL[j], mr = mapR[j];
      outL[off] = xlv[jt][reg] * (1.f - ml) + pL[jt][reg] * ml;
      outR[off] = xrv[jt][reg] * (1.f - mr) + pR[jt][reg] * mr;
    }
  }
}

extern "C" void kernel_launch(void* const* d_in, const int* in_sizes, int n_in,
                              void* d_out, int out_size, void* d_ws, size_t ws_size,
                              hipStream_t stream) {
  const float* x_left = (const float*)d_in[0];
  const float* x_right = (const float*)d_in[1];
  const float* d_left = (const float*)d_in[2];
  const float* d_right = (const float*)d_in[3];
  const float* bn_gamma = (const float*)d_in[4];
  const float* bn_beta = (const float*)d_in[5];
  const float* rb_w1 = (const float*)d_in[6];
  const float* rb_b1 = (const float*)d_in[7];
  const float* rb_w2 = (const float*)d_in[8];
  const float* rb_b2 = (const float*)d_in[9];
  const float* qkv_w = (const float*)d_in[10];
  const float* qkv_b = (const float*)d_in[11];

  float* ws = (float*)d_ws;
  const size_t S = S_ELEMS;
  unsigned short* tL = (unsigned short*)ws;              // S ushorts (conv1 out fp16)
  unsigned short* tR = tL + S;                           // S ushorts (ends at ws+S floats)
  float* knL = ws + 2 * S;           // S floats NHWC [b*HW+p][64]
  float* knR = ws + 3 * S;           // S floats
  unsigned short* vnL = (unsigned short*)(ws + 4 * S);   // S ushorts NHWC
  unsigned short* vnR = vnL + S;                         // S ushorts
  float* qnL = ws + 5 * S;           // S floats NHWC
  float* qnR = ws + 6 * S;           // S floats

  // partial/stats at head of d_out: written by bn kernels, read by conv kernels,
  // overwritten by attn's blend at the end (stream order guarantees safety).
  float* out_left = (float*)d_out;
  float* out_right = out_left + S;
  float2* partial = (float2*)d_out;              // 2048 float2
  float* stats = (float*)d_out + 4096;           // 256 floats

  bn_part_k<<<2048, 256, 0, stream>>>(x_left, x_right, partial);
  bn_fin_k<<<1, 128, 0, stream>>>(partial, bn_gamma, bn_beta, stats);

  conv1_k<<<8192, 256, 0, stream>>>(x_left, x_right, rb_w1, rb_b1, stats, tL, tR);
  conv2_qkv_k<<<8192, 256, 0, stream>>>(tL, tR, x_left, x_right, rb_w2, rb_b2,
                                        qkv_w, qkv_b, stats,
                                        qnL, qnR, knL, knR, vnL, vnR);
  attn_k<<<4096, 256, 0, stream>>>(qnL, qnR, knL, knR, vnL, vnR,
                                   d_left, d_right, x_left, x_right,
                                   out_left, out_right);
}

// Round 23
// 601.529 us; speedup vs baseline: 1.0418x; 1.0324x over previous
//
#include <hip/hip_runtime.h>
#include <cstdint>

#define HW 131072        // H*W
#define S_ELEMS 16777216 // B*C*H*W

typedef __attribute__((ext_vector_type(8))) _Float16 f16x8;
typedef __attribute__((ext_vector_type(4))) _Float16 f16x4;
typedef __attribute__((ext_vector_type(4))) float f32x4;

__device__ __forceinline__ float h2f(unsigned short u) {
  return (float)__builtin_bit_cast(_Float16, u);
}
__device__ __forceinline__ unsigned short f2h(float f) {
  return __builtin_bit_cast(unsigned short, (_Float16)f);
}
#define KST 72

// ---------------- BN stats stage 1: partial sums (2 sides x 64 c x 16 slabs) ----------------
__global__ __launch_bounds__(256) void bn_part_k(const float* __restrict__ xL,
                                                 const float* __restrict__ xR,
                                                 float2* __restrict__ partial) {
  int bid = blockIdx.x;
  int side = bid >> 10, rest = bid & 1023;
  int c = rest >> 4, sl = rest & 15;
  const float* x = side ? xR : xL;
  const float4* p = (const float4*)(x + ((size_t)((sl >> 3) * 64 + c)) * HW + (size_t)(sl & 7) * 16384);
  float s1 = 0.f, s2 = 0.f;
  for (int i = threadIdx.x; i < 4096; i += 256) {
    float4 v = p[i];
    s1 += v.x + v.y + v.z + v.w;
    s2 += v.x * v.x + v.y * v.y + v.z * v.z + v.w * v.w;
  }
  for (int m = 32; m; m >>= 1) {
    s1 += __shfl_xor(s1, m, 64);
    s2 += __shfl_xor(s2, m, 64);
  }
  __shared__ float r1[4], r2[4];
  int wv = threadIdx.x >> 6;
  if ((threadIdx.x & 63) == 0) { r1[wv] = s1; r2[wv] = s2; }
  __syncthreads();
  if (threadIdx.x == 0) {
    partial[bid] = make_float2(r1[0] + r1[1] + r1[2] + r1[3], r2[0] + r2[1] + r2[2] + r2[3]);
  }
}

// ---------------- BN stats stage 2: finalize scale/shift ----------------
__global__ __launch_bounds__(128) void bn_fin_k(const float2* __restrict__ partial,
                                                const float* __restrict__ gamma,
                                                const float* __restrict__ beta,
                                                float* __restrict__ stats) {
  int tid = threadIdx.x;  // 0..127: side*64 + c
  int side = tid >> 6, c = tid & 63;
  float s1 = 0.f, s2 = 0.f;
  const float2* p = partial + (side * 1024 + c * 16);
  for (int s = 0; s < 16; ++s) { float2 v = p[s]; s1 += v.x; s2 += v.y; }
  float mu = s1 / 262144.f;
  float var = s2 / 262144.f - mu * mu;
  float rs = rsqrtf(var + 1e-5f);
  float sc = rs * gamma[c];
  stats[side * 128 + c] = sc;
  stats[side * 128 + 64 + c] = beta[c] - mu * sc;
}

// ---------------- conv1 via MFMA implicit GEMM: bn(x) fp16 -> 9-tap MFMA -> leaky -> t fp16 --
__global__ __launch_bounds__(256) void conv1_k(const float* __restrict__ xL,
                                               const float* __restrict__ xR,
                                               const float* __restrict__ wgt,
                                               const float* __restrict__ bias,
                                               const float* __restrict__ stats,
                                               unsigned short* __restrict__ tL,
                                               unsigned short* __restrict__ tR) {
  __shared__ __align__(16) unsigned short sInH[16 * 372];
  __shared__ __align__(16) float sW1r[2304];  // raw w1 [o][ci][9]
  __shared__ float sB1[16], sSc[16], sSh[16];
  int bid = blockIdx.x;
  int side = bid >> 12, rest = bid & 4095;
  int tw = rest & 15, th = (rest >> 4) & 31, g = (rest >> 9) & 3, b = rest >> 11;
  const float* in = side ? xR : xL;
  unsigned short* out = side ? tR : tL;
  const float* ss = stats + side * 128;
  int tid = threadIdx.x;
  const int lane = tid & 63, wv = tid >> 6;
  const int l15 = lane & 15, lg = lane >> 4;

  for (int e = tid; e < 2304; e += 256) sW1r[e] = wgt[g * 2304 + e];
  if (tid < 16) {
    sB1[tid] = bias[g * 16 + tid];
    sSc[tid] = ss[g * 16 + tid];
    sSh[tid] = ss[64 + g * 16 + tid];
  }
  __syncthreads();  // RACE FIX: sSc/sSh visible before staging reads them
  int h0 = th * 8 - 1, w0 = tw * 32 - 1;
  const float* inb = in + ((size_t)(b * 64 + g * 16)) * HW;
  for (int e = tid; e < 5440; e += 256) {
    int ci = e / 340, rem = e - ci * 340, r = rem / 34, c = rem - r * 34;
    int h = h0 + r, w = w0 + c;
    unsigned short v = 0;
    if ((unsigned)h < 256u && (unsigned)w < 512u) {
      v = f2h(inb[(size_t)ci * HW + h * 512 + w] * sSc[ci] + sSh[ci]);
    }
    sInH[ci * 372 + r * 36 + c] = v;
  }
  __syncthreads();

  f16x4 W1H[9], W1L[9];
#pragma unroll
  for (int tap = 0; tap < 9; ++tap) {
#pragma unroll
    for (int i = 0; i < 4; ++i) {
      float f = sW1r[l15 * 144 + (4 * lg + i) * 9 + tap];
      _Float16 h = (_Float16)f;
      W1H[tap][i] = h;
      W1L[tap][i] = (_Float16)(f - (float)h);
    }
  }
  float b14[4];
#pragma unroll
  for (int r = 0; r < 4; ++r) b14[r] = sB1[4 * lg + r];

#pragma unroll
  for (int j = 0; j < 4; ++j) {
    int ct = 4 * wv + j;
    int px = ct * 16 + l15;
    int prow = px >> 5, pcol = px & 31;
    const unsigned short* p0 = sInH + (4 * lg) * 372 + prow * 36 + pcol;
    f32x4 acc;
#pragma unroll
    for (int r = 0; r < 4; ++r) acc[r] = b14[r];
#pragma unroll
    for (int kh = 0; kh < 3; ++kh) {
#pragma unroll
      for (int kw = 0; kw < 3; ++kw) {
        int toff = kh * 36 + kw;
        f16x4 it;
#pragma unroll
        for (int i = 0; i < 4; ++i)
          it[i] = __builtin_bit_cast(_Float16, p0[i * 372 + toff]);
        acc = __builtin_amdgcn_mfma_f32_16x16x16f16(W1H[kh * 3 + kw], it, acc, 0, 0, 0);
        acc = __builtin_amdgcn_mfma_f32_16x16x16f16(W1L[kh * 3 + kw], it, acc, 0, 0, 0);
      }
    }
    int hpix = th * 8 + prow, wpix = tw * 32 + pcol;
    size_t rowoff = (size_t)hpix * 512 + wpix;
#pragma unroll
    for (int r = 0; r < 4; ++r) {
      float a = acc[r];
      a = a > 0.f ? a : 0.1f * a;
      out[((size_t)(b * 64 + g * 16 + 4 * lg + r)) * HW + rowoff] = f2h(a);
    }
  }
}

// ---------------- fused conv2(MFMA implicit GEMM) + residual + qkv(MFMA); both sides --------
__global__ __launch_bounds__(256) void conv2_qkv_k(
    const unsigned short* __restrict__ tL, const unsigned short* __restrict__ tR,
    const float* __restrict__ xL, const float* __restrict__ xR,
    const float* __restrict__ w2g, const float* __restrict__ b2g,
    const float* __restrict__ wq, const float* __restrict__ bq,
    const float* __restrict__ stats,
    float* __restrict__ qnL, float* __restrict__ qnR,
    float* __restrict__ knL, float* __restrict__ knR,
    unsigned short* __restrict__ vnL, unsigned short* __restrict__ vnR) {
  __shared__ __align__(16) unsigned short sInH[16 * 372];
  __shared__ __align__(16) float sW2r[2304];
  __shared__ __align__(16) float sWq[768];
  __shared__ float sB2[16], sBq[48], sSc[16], sSh[16];

  int bid = blockIdx.x;
  int side = bid >> 12, rest = bid & 4095;
  int tw = rest & 15, th = (rest >> 4) & 31, g = (rest >> 9) & 3, b = rest >> 11;
  const unsigned short* t = side ? tR : tL;
  const float* x = side ? xR : xL;
  float* qn = side ? qnR : qnL;
  float* kn = side ? knR : knL;
  unsigned short* vn = side ? vnR : vnL;
  const float* ss = stats + side * 128;
  int tid = threadIdx.x;
  const int lane = tid & 63, wv = tid >> 6;
  const int l15 = lane & 15, lg = lane >> 4;

  float resx[4][4];
#pragma unroll
  for (int j = 0; j < 4; ++j) {
    int px = (4 * wv + j) * 16 + l15;
    int hpix = th * 8 + (px >> 5), wpix = tw * 32 + (px & 31);
    size_t rowoff = (size_t)hpix * 512 + wpix;
#pragma unroll
    for (int r = 0; r < 4; ++r)
      resx[j][r] = x[((size_t)(b * 64 + g * 16 + 4 * lg + r)) * HW + rowoff];
  }

  for (int e = tid; e < 2304; e += 256) sW2r[e] = w2g[g * 2304 + e];
  for (int e = tid; e < 768; e += 256) {
    int oo = e >> 4, ci = e & 15;
    sWq[e] = wq[(g * 48 + oo) * 16 + ci];
  }
  if (tid < 48) sBq[tid] = bq[g * 48 + tid];
  if (tid < 16) {
    sB2[tid] = b2g[g * 16 + tid];
    sSc[tid] = ss[g * 16 + tid];
    sSh[tid] = ss[64 + g * 16 + tid];
  }

  int h0 = th * 8 - 1, w0 = tw * 32 - 1;
  const unsigned short* inb = t + ((size_t)(b * 64 + g * 16)) * HW;
  for (int e = tid; e < 5440; e += 256) {
    int ci = e / 340, rem = e - ci * 340, r = rem / 34, c = rem - r * 34;
    int h = h0 + r, w = w0 + c;
    unsigned short v = 0;
    if ((unsigned)h < 256u && (unsigned)w < 512u) {
      v = inb[(size_t)ci * HW + h * 512 + w];
    }
    sInH[ci * 372 + r * 36 + c] = v;
  }
  __syncthreads();

  f16x4 W2H[9], W2L[9];
#pragma unroll
  for (int tap = 0; tap < 9; ++tap) {
#pragma unroll
    for (int i = 0; i < 4; ++i) {
      float f = sW2r[l15 * 144 + (4 * lg + i) * 9 + tap];
      _Float16 h = (_Float16)f;
      W2H[tap][i] = h;
      W2L[tap][i] = (_Float16)(f - (float)h);
    }
  }
  f16x4 WqH[3], WqL[3];
#pragma unroll
  for (int rt = 0; rt < 3; ++rt) {
    float4 wvv = *(const float4*)(sWq + (rt * 16 + l15) * 16 + 4 * lg);
#pragma unroll
    for (int i = 0; i < 4; ++i) {
      float f = ((float*)&wvv)[i];
      _Float16 h = (_Float16)f;
      WqH[rt][i] = h;
      WqL[rt][i] = (_Float16)(f - (float)h);
    }
  }
  float sc4[4], sh4[4], b24[4];
#pragma unroll
  for (int r = 0; r < 4; ++r) {
    sc4[r] = sSc[4 * lg + r];
    sh4[r] = sSh[4 * lg + r];
    b24[r] = sB2[4 * lg + r];
  }

#pragma unroll
  for (int j = 0; j < 4; ++j) {
    int ct = 4 * wv + j;
    int px = ct * 16 + l15;
    int prow = px >> 5, pcol = px & 31;
    const unsigned short* p0 = sInH + (4 * lg) * 372 + prow * 36 + pcol;
    f32x4 acc;
#pragma unroll
    for (int r = 0; r < 4; ++r) acc[r] = b24[r];
#pragma unroll
    for (int kh = 0; kh < 3; ++kh) {
#pragma unroll
      for (int kw = 0; kw < 3; ++kw) {
        int toff = kh * 36 + kw;
        f16x4 it;
#pragma unroll
        for (int i = 0; i < 4; ++i)
          it[i] = __builtin_bit_cast(_Float16, p0[i * 372 + toff]);
        acc = __builtin_amdgcn_mfma_f32_16x16x16f16(W2H[kh * 3 + kw], it, acc, 0, 0, 0);
        acc = __builtin_amdgcn_mfma_f32_16x16x16f16(W2L[kh * 3 + kw], it, acc, 0, 0, 0);
      }
    }
#pragma unroll
    for (int r = 0; r < 4; ++r) acc[r] += resx[j][r] * sc4[r] + sh4[r];
    f16x4 rh, rl;
#pragma unroll
    for (int i = 0; i < 4; ++i) {
      _Float16 h = (_Float16)acc[i];
      rh[i] = h;
      rl[i] = (_Float16)(acc[i] - (float)h);
    }
    int hpix = th * 8 + prow, wpix = tw * 32 + pcol;
    size_t pxbase = ((size_t)b * HW + hpix * 512 + wpix) * 64;
#pragma unroll
    for (int rt = 0; rt < 3; ++rt) {
      f32x4 a;
#pragma unroll
      for (int r = 0; r < 4; ++r) a[r] = sBq[rt * 16 + 4 * lg + r];
      a = __builtin_amdgcn_mfma_f32_16x16x16f16(WqH[rt], rh, a, 0, 0, 0);
      a = __builtin_amdgcn_mfma_f32_16x16x16f16(WqH[rt], rl, a, 0, 0, 0);
      a = __builtin_amdgcn_mfma_f32_16x16x16f16(WqL[rt], rh, a, 0, 0, 0);
      int ob = g * 48 + rt * 16 + 4 * lg;
      if (ob < 64) {
        *(float4*)(qn + pxbase + ob) = *(float4*)&a;
      } else if (ob < 128) {
        *(float4*)(kn + pxbase + (ob - 64)) = *(float4*)&a;
      } else {
        uint2 pk;
        pk.x = (uint32_t)f2h(a[0]) | ((uint32_t)f2h(a[1]) << 16);
        pk.y = (uint32_t)f2h(a[2]) | ((uint32_t)f2h(a[3]) << 16);
        *(uint2*)(vn + pxbase + (ob - 128)) = pk;
      }
    }
  }
}

// ---------------- fused per-window attention: fp16-K, split-Q, fp16-M; high occupancy ----
__global__ __launch_bounds__(256, 4) void attn_k(
    const float* __restrict__ qLn, const float* __restrict__ qRn,  // NHWC fp32
    const float* __restrict__ kLn, const float* __restrict__ kRn,  // NHWC fp32
    const unsigned short* __restrict__ vLn, const unsigned short* __restrict__ vRn, // NHWC fp16
    const float* __restrict__ dL, const float* __restrict__ dR,
    const float* __restrict__ xL, const float* __restrict__ xR,
    float* outL, float* outR) {
  // XCD-aware swizzle: consecutive windows -> same XCD L2 (4096 % 8 == 0, bijective)
  const int orig = blockIdx.x;
  const int n = (orig & 7) * 512 + (orig >> 3);
  const int b = n >> 11, hb = (n >> 6) & 31, wb = n & 63;
  const int tid = threadIdx.x;
  const int lane = tid & 63, w = tid >> 6;
  const int l15 = lane & 15, lg = lane >> 4;

  // K fp16 (stride 72) per dir; region reused after B2.5 as fp16 M (stride 72).
  // LDS ~19.5KB -> 8 blocks/CU (occupancy 2x vs hi/lo-K + fp32-M variant).
  __shared__ __align__(16) unsigned short sK[2 * 64 * KST];  // 18432 B
  __shared__ float meanA[8], meanB[8], qsA[64], qsB[64], mapL[64], mapR[64];
  unsigned short* KHA = sK;
  unsigned short* KHB = sK + 64 * KST;
  unsigned short* MHA = sK;            // fp16 M overlay, stride 72
  unsigned short* MHB = sK + 64 * KST;

  const float* dLb = dL + (size_t)b * HW;
  const float* dRb = dR + (size_t)b * HW;
  const size_t nb = (size_t)b * HW;

  // ---- K gather (NHWC): 2 iters, 8 channels per thread per dir; store fp16 ----
  const int cc0 = (wb & 7) * 8;
#pragma unroll
  for (int it = 0; it < 2; ++it) {
    int slot = tid + 256 * it;           // 0..511
    int c2 = slot & 63, k8 = slot >> 6;  // k8 0..7
    int hh = 4 * c2 + (hb >> 3);
    int ww = (hb & 7) * 64 + k8 * 8 + (wb >> 3);
    int dpos = hh * 512 + ww;
    int iwr = ww - (int)dLb[dpos]; iwr = min(max(iwr, 0), 511);
    int iwl = ww + (int)dRb[dpos]; iwl = min(max(iwl, 0), 511);
    const float* pr = kRn + (nb + hh * 512 + iwr) * 64 + cc0;
    const float* pl = kLn + (nb + hh * 512 + iwl) * 64 + cc0;
    float fr[8], fl[8];
    *(float4*)&fr[0] = *(const float4*)pr;
    *(float4*)&fr[4] = *(const float4*)(pr + 4);
    *(float4*)&fl[0] = *(const float4*)pl;
    *(float4*)&fl[4] = *(const float4*)(pl + 4);
#pragma unroll
    for (int kl = 0; kl < 8; ++kl) {
      int k = 8 * k8 + kl;
      KHA[k * KST + c2] = f2h(fr[kl]);
      KHB[k * KST + c2] = f2h(fl[kl]);
    }
  }

  // ---- Q load (NHWC fp32) + hi/lo split (registers only) ----
  const int jr = 16 * w + l15;
  const int hp = hb * 8 + (jr >> 3), wp = wb * 8 + (jr & 7);
  const int gpix = hp * 512 + wp;
  const float* qlp = qLn + (nb + gpix) * 64;
  const float* qrp = qRn + (nb + gpix) * 64;
  float qv0[8], qv1[8], qw0[8], qw1[8];
  *(float4*)&qv0[0] = *(const float4*)(qlp + 8 * lg);
  *(float4*)&qv0[4] = *(const float4*)(qlp + 8 * lg + 4);
  *(float4*)&qv1[0] = *(const float4*)(qlp + 32 + 8 * lg);
  *(float4*)&qv1[4] = *(const float4*)(qlp + 32 + 8 * lg + 4);
  *(float4*)&qw0[0] = *(const float4*)(qrp + 8 * lg);
  *(float4*)&qw0[4] = *(const float4*)(qrp + 8 * lg + 4);
  *(float4*)&qw1[0] = *(const float4*)(qrp + 32 + 8 * lg);
  *(float4*)&qw1[4] = *(const float4*)(qrp + 32 + 8 * lg + 4);
  f16x8 qah0, qal0, qah1, qal1, qbh0, qbl0, qbh1, qbl1;
#pragma unroll
  for (int e = 0; e < 8; ++e) {
    _Float16 h;
    h = (_Float16)qv0[e]; qah0[e] = h; qal0[e] = (_Float16)(qv0[e] - (float)h);
    h = (_Float16)qv1[e]; qah1[e] = h; qal1[e] = (_Float16)(qv1[e] - (float)h);
    h = (_Float16)qw0[e]; qbh0[e] = h; qbl0[e] = (_Float16)(qw0[e] - (float)h);
    h = (_Float16)qw1[e]; qbh1[e] = h; qbl1[e] = (_Float16)(qw1[e] - (float)h);
  }

  // ---- V fragments (NHWC fp16: one b128 per (h,dir)) ----
  int4 vAr[2], vBr[2];
  {
    const int cv = 16 * w + l15;
#pragma unroll
    for (int h = 0; h < 2; ++h) {
      int hi = 4 * h + lg;
      int hh = 4 * cv + (hb >> 3);
      int ww = (hb & 7) * 64 + hi * 8 + (wb >> 3);
      int dpos = hh * 512 + ww;
      int iwr = ww - (int)dLb[dpos]; iwr = min(max(iwr, 0), 511);
      int iwl = ww + (int)dRb[dpos]; iwl = min(max(iwl, 0), 511);
      vAr[h] = *(const int4*)(vRn + (nb + hh * 512 + iwr) * 64 + cc0);
      vBr[h] = *(const int4*)(vLn + (nb + hh * 512 + iwl) * 64 + cc0);
    }
  }
  __syncthreads();  // B1: K staged

  // ---- K means per (dir,hi) over (wi,c) from the SAME rounded K the MFMA sees ----
  {
    int grp = tid >> 4, i = tid & 15;
    int dir = grp >> 3, hi = grp & 7;
    int off0 = (8 * hi + (i >> 1)) * KST + (i & 1) * 32;
    const unsigned short* srcH = (dir ? KHB : KHA) + off0;
    float s = 0.f;
#pragma unroll
    for (int q = 0; q < 32; ++q) s += h2f(srcH[q]);
    for (int m = 8; m; m >>= 1) s += __shfl_xor(s, m, 64);
    if (i == 0) (dir ? meanB : meanA)[hi] = s * (1.f / 512.f);
  }
  // ---- qsum[j] (fp32 exact) ----
  {
    float sa = 0.f, sb = 0.f;
#pragma unroll
    for (int e = 0; e < 8; ++e) {
      sa += qv0[e] + qv1[e];
      sb += qw0[e] + qw1[e];
    }
    sa += __shfl_xor(sa, 16, 64); sa += __shfl_xor(sa, 32, 64);
    sb += __shfl_xor(sb, 16, 64); sb += __shfl_xor(sb, 32, 64);
    if (lane < 16) { qsA[jr] = sa; qsB[jr] = sb; }
  }
  __syncthreads();  // B2: means + qsums ready

  // ---- QK^T: (qh+ql) . k16 -> 2 MFMA per K-chunk ----
  f32x4 sA[4], sB[4];
#pragma unroll
  for (int t = 0; t < 4; ++t) { sA[t] = (f32x4){0.f, 0.f, 0.f, 0.f}; sB[t] = sA[t]; }
#pragma unroll
  for (int t = 0; t < 4; ++t) {
    int ro = (16 * t + l15) * KST + 8 * lg;
    f16x8 kh0 = *(const f16x8*)(KHA + ro);
    f16x8 kh1 = *(const f16x8*)(KHA + ro + 32);
    sA[t] = __builtin_amdgcn_mfma_f32_16x16x32_f16(qah0, kh0, sA[t], 0, 0, 0);
    sA[t] = __builtin_amdgcn_mfma_f32_16x16x32_f16(qal0, kh0, sA[t], 0, 0, 0);
    sA[t] = __builtin_amdgcn_mfma_f32_16x16x32_f16(qah1, kh1, sA[t], 0, 0, 0);
    sA[t] = __builtin_amdgcn_mfma_f32_16x16x32_f16(qal1, kh1, sA[t], 0, 0, 0);
    f16x8 mh0 = *(const f16x8*)(KHB + ro);
    f16x8 mh1 = *(const f16x8*)(KHB + ro + 32);
    sB[t] = __builtin_amdgcn_mfma_f32_16x16x32_f16(qbh0, mh0, sB[t], 0, 0, 0);
    sB[t] = __builtin_amdgcn_mfma_f32_16x16x32_f16(qbl0, mh0, sB[t], 0, 0, 0);
    sB[t] = __builtin_amdgcn_mfma_f32_16x16x32_f16(qbh1, mh1, sB[t], 0, 0, 0);
    sB[t] = __builtin_amdgcn_mfma_f32_16x16x32_f16(qbl1, mh1, sB[t], 0, 0, 0);
  }
  // ---- mean-fold correction + in-register softmax over k ----
  {
    float qra[4], qrb2[4];
#pragma unroll
    for (int reg = 0; reg < 4; ++reg) {
      qra[reg] = qsA[16 * w + 4 * lg + reg];
      qrb2[reg] = qsB[16 * w + 4 * lg + reg];
    }
#pragma unroll
    for (int t = 0; t < 4; ++t) {
      float mA_ = meanA[2 * t + (l15 >> 3)];
      float mB_ = meanB[2 * t + (l15 >> 3)];
#pragma unroll
      for (int reg = 0; reg < 4; ++reg) {
        sA[t][reg] -= qra[reg] * mA_;
        sB[t][reg] -= qrb2[reg] * mB_;
      }
    }
#pragma unroll
    for (int reg = 0; reg < 4; ++reg) {
      float ma = sA[0][reg], mb = sB[0][reg];
#pragma unroll
      for (int t = 1; t < 4; ++t) { ma = fmaxf(ma, sA[t][reg]); mb = fmaxf(mb, sB[t][reg]); }
#pragma unroll
      for (int m = 1; m <= 8; m <<= 1) {
        ma = fmaxf(ma, __shfl_xor(ma, m, 64));
        mb = fmaxf(mb, __shfl_xor(mb, m, 64));
      }
      float sa = 0.f, sb = 0.f;
#pragma unroll
      for (int t = 0; t < 4; ++t) {
        float ea = __expf(sA[t][reg] - ma), eb = __expf(sB[t][reg] - mb);
        sA[t][reg] = ea; sB[t][reg] = eb;
        sa += ea; sb += eb;
      }
#pragma unroll
      for (int m = 1; m <= 8; m <<= 1) {
        sa += __shfl_xor(sa, m, 64);
        sb += __shfl_xor(sb, m, 64);
      }
      float ra = 1.f / sa, rb = 1.f / sb;
#pragma unroll
      for (int t = 0; t < 4; ++t) { sA[t][reg] *= ra; sB[t][reg] *= rb; }
    }
  }
  __syncthreads();  // B2.5: all K reads done; overlay fp16 M onto K region

  // ---- write M fp16 (stride 72; round-7-proven PV fragment layout) ----
#pragma unroll
  for (int t = 0; t < 4; ++t)
#pragma unroll
    for (int reg = 0; reg < 4; ++reg) {
      int jrow = 16 * w + 4 * lg + reg, kcol = 16 * t + l15;
      MHA[jrow * KST + kcol] = f2h(sA[t][reg]);
      MHB[jrow * KST + kcol] = f2h(sB[t][reg]);
    }
  __syncthreads();  // B3: M complete

  // ---- PV via MFMA (fp16 M read directly): X^T[c][j] = sum_k V_sel[k][c] * M[j][k] ----
  f32x4 pL[4], pR[4];
#pragma unroll
  for (int t = 0; t < 4; ++t) { pL[t] = (f32x4){0.f, 0.f, 0.f, 0.f}; pR[t] = pL[t]; }
#pragma unroll
  for (int h = 0; h < 2; ++h) {
    f16x8 va = __builtin_bit_cast(f16x8, vAr[h]);
    f16x8 vb = __builtin_bit_cast(f16x8, vBr[h]);
#pragma unroll
    for (int jt = 0; jt < 4; ++jt) {
      f16x8 ma = *(const f16x8*)(MHA + (16 * jt + l15) * KST + 32 * h + 8 * lg);
      f16x8 mb = *(const f16x8*)(MHB + (16 * jt + l15) * KST + 32 * h + 8 * lg);
      pL[jt] = __builtin_amdgcn_mfma_f32_16x16x32_f16(va, ma, pL[jt], 0, 0, 0);
      pR[jt] = __builtin_amdgcn_mfma_f32_16x16x32_f16(vb, mb, pR[jt], 0, 0, 0);
    }
  }
  // ---- x blend prefetch (T14): issue loads before m_relax, use after B4 ----
  float xlv[4][4], xrv[4][4];
#pragma unroll
  for (int jt = 0; jt < 4; ++jt)
#pragma unroll
    for (int reg = 0; reg < 4; ++reg) {
      int c = 16 * w + 4 * lg + reg;
      int j = 16 * jt + l15;
      int hp2 = hb * 8 + (j >> 3), wp2 = wb * 8 + (j & 7);
      size_t off = ((size_t)(b * 64 + c)) * HW + hp2 * 512 + wp2;
      xlv[jt][reg] = xL[off];
      xrv[jt][reg] = xR[off];
    }
  // ---- m_relax band + einsum + tanh from fp16 M (128 threads) ----
  if (tid < 128) {
    int dir = tid >> 6, j = tid & 63;
    const unsigned short* Mrow = dir ? MHB : MHA;
    const unsigned short* Mcol = dir ? MHA : MHB;
    float acc = 0.f;
    for (int k = 0; k < 64; ++k) {
      float rx = 0.f;
#pragma unroll
      for (int i = -2; i <= 2; ++i) {
        int jj = j + i;
        if ((unsigned)jj < 64u) rx += h2f(Mrow[jj * KST + k]);
      }
      acc += rx * h2f(Mcol[k * KST + j]);
    }
    (dir ? mapR : mapL)[j] = tanhf(5.f * acc);
  }
  __syncthreads();  // B4: maps ready

  // ---- blend + store ----
#pragma unroll
  for (int jt = 0; jt < 4; ++jt) {
#pragma unroll
    for (int reg = 0; reg < 4; ++reg) {
      int c = 16 * w + 4 * lg + reg;
      int j = 16 * jt + l15;
      int hp2 = hb * 8 + (j >> 3), wp2 = wb * 8 + (j & 7);
      size_t off = ((size_t)(b * 64 + c)) * HW + hp2 * 512 + wp2;
      float ml = mapL[j], mr = mapR[j];
      outL[off] = xlv[jt][reg] * (1.f - ml) + pL[jt][reg] * ml;
      outR[off] = xrv[jt][reg] * (1.f - mr) + pR[jt][reg] * mr;
    }
  }
}

extern "C" void kernel_launch(void* const* d_in, const int* in_sizes, int n_in,
                              void* d_out, int out_size, void* d_ws, size_t ws_size,
                              hipStream_t stream) {
  const float* x_left = (const float*)d_in[0];
  const float* x_right = (const float*)d_in[1];
  const float* d_left = (const float*)d_in[2];
  const float* d_right = (const float*)d_in[3];
  const float* bn_gamma = (const float*)d_in[4];
  const float* bn_beta = (const float*)d_in[5];
  const float* rb_w1 = (const float*)d_in[6];
  const float* rb_b1 = (const float*)d_in[7];
  const float* rb_w2 = (const float*)d_in[8];
  const float* rb_b2 = (const float*)d_in[9];
  const float* qkv_w = (const float*)d_in[10];
  const float* qkv_b = (const float*)d_in[11];

  float* ws = (float*)d_ws;
  const size_t S = S_ELEMS;
  unsigned short* tL = (unsigned short*)ws;              // S ushorts (conv1 out fp16)
  unsigned short* tR = tL + S;                           // S ushorts
  float* knL = ws + 2 * S;           // S floats NHWC [b*HW+p][64]
  float* knR = ws + 3 * S;           // S floats
  unsigned short* vnL = (unsigned short*)(ws + 4 * S);   // S ushorts NHWC
  unsigned short* vnR = vnL + S;                         // S ushorts
  float* qnL = ws + 5 * S;           // S floats NHWC
  float* qnR = ws + 6 * S;           // S floats

  // partial/stats at head of d_out: written by bn kernels, read by conv kernels,
  // overwritten by attn's blend at the end (stream order guarantees safety).
  float* out_left = (float*)d_out;
  float* out_right = out_left + S;
  float2* partial = (float2*)d_out;              // 2048 float2
  float* stats = (float*)d_out + 4096;           // 256 floats

  bn_part_k<<<2048, 256, 0, stream>>>(x_left, x_right, partial);
  bn_fin_k<<<1, 128, 0, stream>>>(partial, bn_gamma, bn_beta, stats);

  conv1_k<<<8192, 256, 0, stream>>>(x_left, x_right, rb_w1, rb_b1, stats, tL, tR);
  conv2_qkv_k<<<8192, 256, 0, stream>>>(tL, tR, x_left, x_right, rb_w2, rb_b2,
                                        qkv_w, qkv_b, stats,
                                        qnL, qnR, knL, knR, vnL, vnR);
  attn_k<<<4096, 256, 0, stream>>>(qnL, qnR, knL, knR, vnL, vnR,
                                   d_left, d_right, x_left, x_right,
                                   out_left, out_right);
}

// Round 24
// 534.630 us; speedup vs baseline: 1.1722x; 1.1251x over previous
//
#include <hip/hip_runtime.h>
#include <cstdint>

#define HW 131072        // H*W
#define S_ELEMS 16777216 // B*C*H*W

typedef __attribute__((ext_vector_type(8))) _Float16 f16x8;
typedef __attribute__((ext_vector_type(4))) _Float16 f16x4;
typedef __attribute__((ext_vector_type(4))) float f32x4;

__device__ __forceinline__ float h2f(unsigned short u) {
  return (float)__builtin_bit_cast(_Float16, u);
}
__device__ __forceinline__ unsigned short f2h(float f) {
  return __builtin_bit_cast(unsigned short, (_Float16)f);
}
#define KST 72

// ---------------- BN stats stage 1: partial sums (2 sides x 64 c x 16 slabs) ----------------
__global__ __launch_bounds__(256) void bn_part_k(const float* __restrict__ xL,
                                                 const float* __restrict__ xR,
                                                 float2* __restrict__ partial) {
  int bid = blockIdx.x;
  int side = bid >> 10, rest = bid & 1023;
  int c = rest >> 4, sl = rest & 15;
  const float* x = side ? xR : xL;
  const float4* p = (const float4*)(x + ((size_t)((sl >> 3) * 64 + c)) * HW + (size_t)(sl & 7) * 16384);
  float s1 = 0.f, s2 = 0.f;
  for (int i = threadIdx.x; i < 4096; i += 256) {
    float4 v = p[i];
    s1 += v.x + v.y + v.z + v.w;
    s2 += v.x * v.x + v.y * v.y + v.z * v.z + v.w * v.w;
  }
  for (int m = 32; m; m >>= 1) {
    s1 += __shfl_xor(s1, m, 64);
    s2 += __shfl_xor(s2, m, 64);
  }
  __shared__ float r1[4], r2[4];
  int wv = threadIdx.x >> 6;
  if ((threadIdx.x & 63) == 0) { r1[wv] = s1; r2[wv] = s2; }
  __syncthreads();
  if (threadIdx.x == 0) {
    partial[bid] = make_float2(r1[0] + r1[1] + r1[2] + r1[3], r2[0] + r2[1] + r2[2] + r2[3]);
  }
}

// ---------------- BN stats stage 2: finalize scale/shift ----------------
__global__ __launch_bounds__(128) void bn_fin_k(const float2* __restrict__ partial,
                                                const float* __restrict__ gamma,
                                                const float* __restrict__ beta,
                                                float* __restrict__ stats) {
  int tid = threadIdx.x;  // 0..127: side*64 + c
  int side = tid >> 6, c = tid & 63;
  float s1 = 0.f, s2 = 0.f;
  const float2* p = partial + (side * 1024 + c * 16);
  for (int s = 0; s < 16; ++s) { float2 v = p[s]; s1 += v.x; s2 += v.y; }
  float mu = s1 / 262144.f;
  float var = s2 / 262144.f - mu * mu;
  float rs = rsqrtf(var + 1e-5f);
  float sc = rs * gamma[c];
  stats[side * 128 + c] = sc;
  stats[side * 128 + 64 + c] = beta[c] - mu * sc;
}

// ---------------- conv1 via MFMA implicit GEMM: bn(x) fp16 -> 9-tap MFMA -> leaky -> t fp16 --
__global__ __launch_bounds__(256) void conv1_k(const float* __restrict__ xL,
                                               const float* __restrict__ xR,
                                               const float* __restrict__ wgt,
                                               const float* __restrict__ bias,
                                               const float* __restrict__ stats,
                                               unsigned short* __restrict__ tL,
                                               unsigned short* __restrict__ tR) {
  __shared__ __align__(16) unsigned short sInH[16 * 372];
  __shared__ __align__(16) float sW1r[2304];  // raw w1 [o][ci][9]
  __shared__ float sB1[16], sSc[16], sSh[16];
  int bid = blockIdx.x;
  int side = bid >> 12, rest = bid & 4095;
  int tw = rest & 15, th = (rest >> 4) & 31, g = (rest >> 9) & 3, b = rest >> 11;
  const float* in = side ? xR : xL;
  unsigned short* out = side ? tR : tL;
  const float* ss = stats + side * 128;
  int tid = threadIdx.x;
  const int lane = tid & 63, wv = tid >> 6;
  const int l15 = lane & 15, lg = lane >> 4;

  for (int e = tid; e < 2304; e += 256) sW1r[e] = wgt[g * 2304 + e];
  if (tid < 16) {
    sB1[tid] = bias[g * 16 + tid];
    sSc[tid] = ss[g * 16 + tid];
    sSh[tid] = ss[64 + g * 16 + tid];
  }
  __syncthreads();  // RACE FIX: sSc/sSh visible before staging reads them
  int h0 = th * 8 - 1, w0 = tw * 32 - 1;
  const float* inb = in + ((size_t)(b * 64 + g * 16)) * HW;
  for (int e = tid; e < 5440; e += 256) {
    int ci = e / 340, rem = e - ci * 340, r = rem / 34, c = rem - r * 34;
    int h = h0 + r, w = w0 + c;
    unsigned short v = 0;
    if ((unsigned)h < 256u && (unsigned)w < 512u) {
      v = f2h(inb[(size_t)ci * HW + h * 512 + w] * sSc[ci] + sSh[ci]);
    }
    sInH[ci * 372 + r * 36 + c] = v;
  }
  __syncthreads();

  f16x4 W1H[9], W1L[9];
#pragma unroll
  for (int tap = 0; tap < 9; ++tap) {
#pragma unroll
    for (int i = 0; i < 4; ++i) {
      float f = sW1r[l15 * 144 + (4 * lg + i) * 9 + tap];
      _Float16 h = (_Float16)f;
      W1H[tap][i] = h;
      W1L[tap][i] = (_Float16)(f - (float)h);
    }
  }
  float b14[4];
#pragma unroll
  for (int r = 0; r < 4; ++r) b14[r] = sB1[4 * lg + r];

#pragma unroll
  for (int j = 0; j < 4; ++j) {
    int ct = 4 * wv + j;
    int px = ct * 16 + l15;
    int prow = px >> 5, pcol = px & 31;
    const unsigned short* p0 = sInH + (4 * lg) * 372 + prow * 36 + pcol;
    f32x4 acc;
#pragma unroll
    for (int r = 0; r < 4; ++r) acc[r] = b14[r];
#pragma unroll
    for (int kh = 0; kh < 3; ++kh) {
#pragma unroll
      for (int kw = 0; kw < 3; ++kw) {
        int toff = kh * 36 + kw;
        f16x4 it;
#pragma unroll
        for (int i = 0; i < 4; ++i)
          it[i] = __builtin_bit_cast(_Float16, p0[i * 372 + toff]);
        acc = __builtin_amdgcn_mfma_f32_16x16x16f16(W1H[kh * 3 + kw], it, acc, 0, 0, 0);
        acc = __builtin_amdgcn_mfma_f32_16x16x16f16(W1L[kh * 3 + kw], it, acc, 0, 0, 0);
      }
    }
    int hpix = th * 8 + prow, wpix = tw * 32 + pcol;
    size_t rowoff = (size_t)hpix * 512 + wpix;
#pragma unroll
    for (int r = 0; r < 4; ++r) {
      float a = acc[r];
      a = a > 0.f ? a : 0.1f * a;
      out[((size_t)(b * 64 + g * 16 + 4 * lg + r)) * HW + rowoff] = f2h(a);
    }
  }
}

// ---------------- fused conv2(MFMA implicit GEMM) + residual + qkv(MFMA); fp16 QKV out -----
__global__ __launch_bounds__(256) void conv2_qkv_k(
    const unsigned short* __restrict__ tL, const unsigned short* __restrict__ tR,
    const float* __restrict__ xL, const float* __restrict__ xR,
    const float* __restrict__ w2g, const float* __restrict__ b2g,
    const float* __restrict__ wq, const float* __restrict__ bq,
    const float* __restrict__ stats,
    unsigned short* __restrict__ qnL, unsigned short* __restrict__ qnR,
    unsigned short* __restrict__ knL, unsigned short* __restrict__ knR,
    unsigned short* __restrict__ vnL, unsigned short* __restrict__ vnR) {
  __shared__ __align__(16) unsigned short sInH[16 * 372];
  __shared__ __align__(16) float sW2r[2304];
  __shared__ __align__(16) float sWq[768];
  __shared__ float sB2[16], sBq[48], sSc[16], sSh[16];

  int bid = blockIdx.x;
  int side = bid >> 12, rest = bid & 4095;
  int tw = rest & 15, th = (rest >> 4) & 31, g = (rest >> 9) & 3, b = rest >> 11;
  const unsigned short* t = side ? tR : tL;
  const float* x = side ? xR : xL;
  unsigned short* qn = side ? qnR : qnL;
  unsigned short* kn = side ? knR : knL;
  unsigned short* vn = side ? vnR : vnL;
  const float* ss = stats + side * 128;
  int tid = threadIdx.x;
  const int lane = tid & 63, wv = tid >> 6;
  const int l15 = lane & 15, lg = lane >> 4;

  float resx[4][4];
#pragma unroll
  for (int j = 0; j < 4; ++j) {
    int px = (4 * wv + j) * 16 + l15;
    int hpix = th * 8 + (px >> 5), wpix = tw * 32 + (px & 31);
    size_t rowoff = (size_t)hpix * 512 + wpix;
#pragma unroll
    for (int r = 0; r < 4; ++r)
      resx[j][r] = x[((size_t)(b * 64 + g * 16 + 4 * lg + r)) * HW + rowoff];
  }

  for (int e = tid; e < 2304; e += 256) sW2r[e] = w2g[g * 2304 + e];
  for (int e = tid; e < 768; e += 256) {
    int oo = e >> 4, ci = e & 15;
    sWq[e] = wq[(g * 48 + oo) * 16 + ci];
  }
  if (tid < 48) sBq[tid] = bq[g * 48 + tid];
  if (tid < 16) {
    sB2[tid] = b2g[g * 16 + tid];
    sSc[tid] = ss[g * 16 + tid];
    sSh[tid] = ss[64 + g * 16 + tid];
  }

  int h0 = th * 8 - 1, w0 = tw * 32 - 1;
  const unsigned short* inb = t + ((size_t)(b * 64 + g * 16)) * HW;
  for (int e = tid; e < 5440; e += 256) {
    int ci = e / 340, rem = e - ci * 340, r = rem / 34, c = rem - r * 34;
    int h = h0 + r, w = w0 + c;
    unsigned short v = 0;
    if ((unsigned)h < 256u && (unsigned)w < 512u) {
      v = inb[(size_t)ci * HW + h * 512 + w];
    }
    sInH[ci * 372 + r * 36 + c] = v;
  }
  __syncthreads();

  f16x4 W2H[9], W2L[9];
#pragma unroll
  for (int tap = 0; tap < 9; ++tap) {
#pragma unroll
    for (int i = 0; i < 4; ++i) {
      float f = sW2r[l15 * 144 + (4 * lg + i) * 9 + tap];
      _Float16 h = (_Float16)f;
      W2H[tap][i] = h;
      W2L[tap][i] = (_Float16)(f - (float)h);
    }
  }
  f16x4 WqH[3], WqL[3];
#pragma unroll
  for (int rt = 0; rt < 3; ++rt) {
    float4 wvv = *(const float4*)(sWq + (rt * 16 + l15) * 16 + 4 * lg);
#pragma unroll
    for (int i = 0; i < 4; ++i) {
      float f = ((float*)&wvv)[i];
      _Float16 h = (_Float16)f;
      WqH[rt][i] = h;
      WqL[rt][i] = (_Float16)(f - (float)h);
    }
  }
  float sc4[4], sh4[4], b24[4];
#pragma unroll
  for (int r = 0; r < 4; ++r) {
    sc4[r] = sSc[4 * lg + r];
    sh4[r] = sSh[4 * lg + r];
    b24[r] = sB2[4 * lg + r];
  }

#pragma unroll
  for (int j = 0; j < 4; ++j) {
    int ct = 4 * wv + j;
    int px = ct * 16 + l15;
    int prow = px >> 5, pcol = px & 31;
    const unsigned short* p0 = sInH + (4 * lg) * 372 + prow * 36 + pcol;
    f32x4 acc;
#pragma unroll
    for (int r = 0; r < 4; ++r) acc[r] = b24[r];
#pragma unroll
    for (int kh = 0; kh < 3; ++kh) {
#pragma unroll
      for (int kw = 0; kw < 3; ++kw) {
        int toff = kh * 36 + kw;
        f16x4 it;
#pragma unroll
        for (int i = 0; i < 4; ++i)
          it[i] = __builtin_bit_cast(_Float16, p0[i * 372 + toff]);
        acc = __builtin_amdgcn_mfma_f32_16x16x16f16(W2H[kh * 3 + kw], it, acc, 0, 0, 0);
        acc = __builtin_amdgcn_mfma_f32_16x16x16f16(W2L[kh * 3 + kw], it, acc, 0, 0, 0);
      }
    }
#pragma unroll
    for (int r = 0; r < 4; ++r) acc[r] += resx[j][r] * sc4[r] + sh4[r];
    f16x4 rh, rl;
#pragma unroll
    for (int i = 0; i < 4; ++i) {
      _Float16 h = (_Float16)acc[i];
      rh[i] = h;
      rl[i] = (_Float16)(acc[i] - (float)h);
    }
    int hpix = th * 8 + prow, wpix = tw * 32 + pcol;
    size_t pxbase = ((size_t)b * HW + hpix * 512 + wpix) * 64;
#pragma unroll
    for (int rt = 0; rt < 3; ++rt) {
      f32x4 a;
#pragma unroll
      for (int r = 0; r < 4; ++r) a[r] = sBq[rt * 16 + 4 * lg + r];
      a = __builtin_amdgcn_mfma_f32_16x16x16f16(WqH[rt], rh, a, 0, 0, 0);
      a = __builtin_amdgcn_mfma_f32_16x16x16f16(WqH[rt], rl, a, 0, 0, 0);
      a = __builtin_amdgcn_mfma_f32_16x16x16f16(WqL[rt], rh, a, 0, 0, 0);
      int ob = g * 48 + rt * 16 + 4 * lg;
      uint2 pk;
      pk.x = (uint32_t)f2h(a[0]) | ((uint32_t)f2h(a[1]) << 16);
      pk.y = (uint32_t)f2h(a[2]) | ((uint32_t)f2h(a[3]) << 16);
      if (ob < 64) {
        *(uint2*)(qn + pxbase + ob) = pk;
      } else if (ob < 128) {
        *(uint2*)(kn + pxbase + (ob - 64)) = pk;
      } else {
        *(uint2*)(vn + pxbase + (ob - 128)) = pk;
      }
    }
  }
}

// ---------------- fused per-window attention: all-fp16 QKV, fp16 M ----
__global__ __launch_bounds__(256, 4) void attn_k(
    const unsigned short* __restrict__ qLn, const unsigned short* __restrict__ qRn,  // NHWC fp16
    const unsigned short* __restrict__ kLn, const unsigned short* __restrict__ kRn,  // NHWC fp16
    const unsigned short* __restrict__ vLn, const unsigned short* __restrict__ vRn,  // NHWC fp16
    const float* __restrict__ dL, const float* __restrict__ dR,
    const float* __restrict__ xL, const float* __restrict__ xR,
    float* outL, float* outR) {
  // XCD-aware swizzle: consecutive windows -> same XCD L2 (4096 % 8 == 0, bijective)
  const int orig = blockIdx.x;
  const int n = (orig & 7) * 512 + (orig >> 3);
  const int b = n >> 11, hb = (n >> 6) & 31, wb = n & 63;
  const int tid = threadIdx.x;
  const int lane = tid & 63, w = tid >> 6;
  const int l15 = lane & 15, lg = lane >> 4;

  // K fp16 (stride 72) per dir; region reused after B2.5 as fp16 M (stride 72).
  __shared__ __align__(16) unsigned short sK[2 * 64 * KST];  // 18432 B
  __shared__ float meanA[8], meanB[8], qsA[64], qsB[64], mapL[64], mapR[64];
  unsigned short* KHA = sK;
  unsigned short* KHB = sK + 64 * KST;
  unsigned short* MHA = sK;            // fp16 M overlay, stride 72
  unsigned short* MHB = sK + 64 * KST;

  const float* dLb = dL + (size_t)b * HW;
  const float* dRb = dR + (size_t)b * HW;
  const size_t nb = (size_t)b * HW;

  // ---- K gather (NHWC fp16): 2 iters, one b128 per thread per dir ----
  const int cc0 = (wb & 7) * 8;
#pragma unroll
  for (int it = 0; it < 2; ++it) {
    int slot = tid + 256 * it;           // 0..511
    int c2 = slot & 63, k8 = slot >> 6;  // k8 0..7
    int hh = 4 * c2 + (hb >> 3);
    int ww = (hb & 7) * 64 + k8 * 8 + (wb >> 3);
    int dpos = hh * 512 + ww;
    int iwr = ww - (int)dLb[dpos]; iwr = min(max(iwr, 0), 511);
    int iwl = ww + (int)dRb[dpos]; iwl = min(max(iwl, 0), 511);
    int4 kr = *(const int4*)(kRn + (nb + hh * 512 + iwr) * 64 + cc0);
    int4 kl = *(const int4*)(kLn + (nb + hh * 512 + iwl) * 64 + cc0);
    const unsigned short* krp = (const unsigned short*)&kr;
    const unsigned short* klp = (const unsigned short*)&kl;
#pragma unroll
    for (int kl2 = 0; kl2 < 8; ++kl2) {
      int k = 8 * k8 + kl2;
      KHA[k * KST + c2] = krp[kl2];
      KHB[k * KST + c2] = klp[kl2];
    }
  }

  // ---- Q fragments (NHWC fp16: direct b128 loads) ----
  const int jr = 16 * w + l15;
  const int hp = hb * 8 + (jr >> 3), wp = wb * 8 + (jr & 7);
  const int gpix = hp * 512 + wp;
  const unsigned short* qlp = qLn + (nb + (size_t)gpix) * 64;
  const unsigned short* qrp = qRn + (nb + (size_t)gpix) * 64;
  f16x8 qa0 = *(const f16x8*)(qlp + 8 * lg);
  f16x8 qa1 = *(const f16x8*)(qlp + 32 + 8 * lg);
  f16x8 qb0 = *(const f16x8*)(qrp + 8 * lg);
  f16x8 qb1 = *(const f16x8*)(qrp + 32 + 8 * lg);

  // ---- V fragments (NHWC fp16: one b128 per (h,dir)) ----
  int4 vAr[2], vBr[2];
  {
    const int cv = 16 * w + l15;
#pragma unroll
    for (int h = 0; h < 2; ++h) {
      int hi = 4 * h + lg;
      int hh = 4 * cv + (hb >> 3);
      int ww = (hb & 7) * 64 + hi * 8 + (wb >> 3);
      int dpos = hh * 512 + ww;
      int iwr = ww - (int)dLb[dpos]; iwr = min(max(iwr, 0), 511);
      int iwl = ww + (int)dRb[dpos]; iwl = min(max(iwl, 0), 511);
      vAr[h] = *(const int4*)(vRn + (nb + hh * 512 + iwr) * 64 + cc0);
      vBr[h] = *(const int4*)(vLn + (nb + hh * 512 + iwl) * 64 + cc0);
    }
  }
  __syncthreads();  // B1: K staged

  // ---- K means per (dir,hi) over (wi,c) from the SAME rounded K the MFMA sees ----
  {
    int grp = tid >> 4, i = tid & 15;
    int dir = grp >> 3, hi = grp & 7;
    int off0 = (8 * hi + (i >> 1)) * KST + (i & 1) * 32;
    const unsigned short* srcH = (dir ? KHB : KHA) + off0;
    float s = 0.f;
#pragma unroll
    for (int q = 0; q < 32; ++q) s += h2f(srcH[q]);
    for (int m = 8; m; m >>= 1) s += __shfl_xor(s, m, 64);
    if (i == 0) (dir ? meanB : meanA)[hi] = s * (1.f / 512.f);
  }
  // ---- qsum[j] from the SAME rounded q the MFMA sees ----
  {
    float sa = 0.f, sb = 0.f;
#pragma unroll
    for (int e = 0; e < 8; ++e) {
      sa += (float)qa0[e] + (float)qa1[e];
      sb += (float)qb0[e] + (float)qb1[e];
    }
    sa += __shfl_xor(sa, 16, 64); sa += __shfl_xor(sa, 32, 64);
    sb += __shfl_xor(sb, 16, 64); sb += __shfl_xor(sb, 32, 64);
    if (lane < 16) { qsA[jr] = sa; qsB[jr] = sb; }
  }
  __syncthreads();  // B2: means + qsums ready

  // ---- QK^T: q16 . k16 -> 1 MFMA per K-chunk per dir ----
  f32x4 sA[4], sB[4];
#pragma unroll
  for (int t = 0; t < 4; ++t) { sA[t] = (f32x4){0.f, 0.f, 0.f, 0.f}; sB[t] = sA[t]; }
#pragma unroll
  for (int t = 0; t < 4; ++t) {
    int ro = (16 * t + l15) * KST + 8 * lg;
    f16x8 kh0 = *(const f16x8*)(KHA + ro);
    f16x8 kh1 = *(const f16x8*)(KHA + ro + 32);
    sA[t] = __builtin_amdgcn_mfma_f32_16x16x32_f16(qa0, kh0, sA[t], 0, 0, 0);
    sA[t] = __builtin_amdgcn_mfma_f32_16x16x32_f16(qa1, kh1, sA[t], 0, 0, 0);
    f16x8 mh0 = *(const f16x8*)(KHB + ro);
    f16x8 mh1 = *(const f16x8*)(KHB + ro + 32);
    sB[t] = __builtin_amdgcn_mfma_f32_16x16x32_f16(qb0, mh0, sB[t], 0, 0, 0);
    sB[t] = __builtin_amdgcn_mfma_f32_16x16x32_f16(qb1, mh1, sB[t], 0, 0, 0);
  }
  // ---- mean-fold correction + in-register softmax over k ----
  {
    float qra[4], qrb2[4];
#pragma unroll
    for (int reg = 0; reg < 4; ++reg) {
      qra[reg] = qsA[16 * w + 4 * lg + reg];
      qrb2[reg] = qsB[16 * w + 4 * lg + reg];
    }
#pragma unroll
    for (int t = 0; t < 4; ++t) {
      float mA_ = meanA[2 * t + (l15 >> 3)];
      float mB_ = meanB[2 * t + (l15 >> 3)];
#pragma unroll
      for (int reg = 0; reg < 4; ++reg) {
        sA[t][reg] -= qra[reg] * mA_;
        sB[t][reg] -= qrb2[reg] * mB_;
      }
    }
#pragma unroll
    for (int reg = 0; reg < 4; ++reg) {
      float ma = sA[0][reg], mb = sB[0][reg];
#pragma unroll
      for (int t = 1; t < 4; ++t) { ma = fmaxf(ma, sA[t][reg]); mb = fmaxf(mb, sB[t][reg]); }
#pragma unroll
      for (int m = 1; m <= 8; m <<= 1) {
        ma = fmaxf(ma, __shfl_xor(ma, m, 64));
        mb = fmaxf(mb, __shfl_xor(mb, m, 64));
      }
      float sa = 0.f, sb = 0.f;
#pragma unroll
      for (int t = 0; t < 4; ++t) {
        float ea = __expf(sA[t][reg] - ma), eb = __expf(sB[t][reg] - mb);
        sA[t][reg] = ea; sB[t][reg] = eb;
        sa += ea; sb += eb;
      }
#pragma unroll
      for (int m = 1; m <= 8; m <<= 1) {
        sa += __shfl_xor(sa, m, 64);
        sb += __shfl_xor(sb, m, 64);
      }
      float ra = 1.f / sa, rb = 1.f / sb;
#pragma unroll
      for (int t = 0; t < 4; ++t) { sA[t][reg] *= ra; sB[t][reg] *= rb; }
    }
  }
  __syncthreads();  // B2.5: all K reads done; overlay fp16 M onto K region

  // ---- write M fp16 (stride 72; PV fragment layout) ----
#pragma unroll
  for (int t = 0; t < 4; ++t)
#pragma unroll
    for (int reg = 0; reg < 4; ++reg) {
      int jrow = 16 * w + 4 * lg + reg, kcol = 16 * t + l15;
      MHA[jrow * KST + kcol] = f2h(sA[t][reg]);
      MHB[jrow * KST + kcol] = f2h(sB[t][reg]);
    }
  __syncthreads();  // B3: M complete

  // ---- PV via MFMA: X^T[c][j] = sum_k V_sel[k][c] * M[j][k] ----
  f32x4 pL[4], pR[4];
#pragma unroll
  for (int t = 0; t < 4; ++t) { pL[t] = (f32x4){0.f, 0.f, 0.f, 0.f}; pR[t] = pL[t]; }
#pragma unroll
  for (int h = 0; h < 2; ++h) {
    f16x8 va = __builtin_bit_cast(f16x8, vAr[h]);
    f16x8 vb = __builtin_bit_cast(f16x8, vBr[h]);
#pragma unroll
    for (int jt = 0; jt < 4; ++jt) {
      f16x8 ma = *(const f16x8*)(MHA + (16 * jt + l15) * KST + 32 * h + 8 * lg);
      f16x8 mb = *(const f16x8*)(MHB + (16 * jt + l15) * KST + 32 * h + 8 * lg);
      pL[jt] = __builtin_amdgcn_mfma_f32_16x16x32_f16(va, ma, pL[jt], 0, 0, 0);
      pR[jt] = __builtin_amdgcn_mfma_f32_16x16x32_f16(vb, mb, pR[jt], 0, 0, 0);
    }
  }
  // ---- x blend prefetch (T14): issue loads before m_relax, use after B4 ----
  float xlv[4][4], xrv[4][4];
#pragma unroll
  for (int jt = 0; jt < 4; ++jt)
#pragma unroll
    for (int reg = 0; reg < 4; ++reg) {
      int c = 16 * w + 4 * lg + reg;
      int j = 16 * jt + l15;
      int hp2 = hb * 8 + (j >> 3), wp2 = wb * 8 + (j & 7);
      size_t off = ((size_t)(b * 64 + c)) * HW + hp2 * 512 + wp2;
      xlv[jt][reg] = xL[off];
      xrv[jt][reg] = xR[off];
    }
  // ---- m_relax band + einsum + tanh from fp16 M (128 threads) ----
  if (tid < 128) {
    int dir = tid >> 6, j = tid & 63;
    const unsigned short* Mrow = dir ? MHB : MHA;
    const unsigned short* Mcol = dir ? MHA : MHB;
    float acc = 0.f;
    for (int k = 0; k < 64; ++k) {
      float rx = 0.f;
#pragma unroll
      for (int i = -2; i <= 2; ++i) {
        int jj = j + i;
        if ((unsigned)jj < 64u) rx += h2f(Mrow[jj * KST + k]);
      }
      acc += rx * h2f(Mcol[k * KST + j]);
    }
    (dir ? mapR : mapL)[j] = tanhf(5.f * acc);
  }
  __syncthreads();  // B4: maps ready

  // ---- blend + store ----
#pragma unroll
  for (int jt = 0; jt < 4; ++jt) {
#pragma unroll
    for (int reg = 0; reg < 4; ++reg) {
      int c = 16 * w + 4 * lg + reg;
      int j = 16 * jt + l15;
      int hp2 = hb * 8 + (j >> 3), wp2 = wb * 8 + (j & 7);
      size_t off = ((size_t)(b * 64 + c)) * HW + hp2 * 512 + wp2;
      float ml = mapL[j], mr = mapR[j];
      outL[off] = xlv[jt][reg] * (1.f - ml) + pL[jt][reg] * ml;
      outR[off] = xrv[jt][reg] * (1.f - mr) + pR[jt][reg] * mr;
    }
  }
}

extern "C" void kernel_launch(void* const* d_in, const int* in_sizes, int n_in,
                              void* d_out, int out_size, void* d_ws, size_t ws_size,
                              hipStream_t stream) {
  const float* x_left = (const float*)d_in[0];
  const float* x_right = (const float*)d_in[1];
  const float* d_left = (const float*)d_in[2];
  const float* d_right = (const float*)d_in[3];
  const float* bn_gamma = (const float*)d_in[4];
  const float* bn_beta = (const float*)d_in[5];
  const float* rb_w1 = (const float*)d_in[6];
  const float* rb_b1 = (const float*)d_in[7];
  const float* rb_w2 = (const float*)d_in[8];
  const float* rb_b2 = (const float*)d_in[9];
  const float* qkv_w = (const float*)d_in[10];
  const float* qkv_b = (const float*)d_in[11];

  float* ws = (float*)d_ws;
  const size_t S = S_ELEMS;
  unsigned short* tL = (unsigned short*)ws;               // [0,S) floats: t fp16 both sides
  unsigned short* tR = tL + S;
  unsigned short* qnL = (unsigned short*)(ws + S);        // [S,2S): Q fp16 NHWC
  unsigned short* qnR = qnL + S;
  unsigned short* knL = (unsigned short*)(ws + 2 * S);    // [2S,3S): K fp16 NHWC
  unsigned short* knR = knL + S;
  unsigned short* vnL = (unsigned short*)(ws + 3 * S);    // [3S,4S): V fp16 NHWC
  unsigned short* vnR = vnL + S;

  // partial/stats at head of d_out: written by bn kernels, read by conv kernels,
  // overwritten by attn's blend at the end (stream order guarantees safety).
  float* out_left = (float*)d_out;
  float* out_right = out_left + S;
  float2* partial = (float2*)d_out;              // 2048 float2
  float* stats = (float*)d_out + 4096;           // 256 floats

  bn_part_k<<<2048, 256, 0, stream>>>(x_left, x_right, partial);
  bn_fin_k<<<1, 128, 0, stream>>>(partial, bn_gamma, bn_beta, stats);

  conv1_k<<<8192, 256, 0, stream>>>(x_left, x_right, rb_w1, rb_b1, stats, tL, tR);
  conv2_qkv_k<<<8192, 256, 0, stream>>>(tL, tR, x_left, x_right, rb_w2, rb_b2,
                                        qkv_w, qkv_b, stats,
                                        qnL, qnR, knL, knR, vnL, vnR);
  attn_k<<<4096, 256, 0, stream>>>(qnL, qnR, knL, knR, vnL, vnR,
                                   d_left, d_right, x_left, x_right,
                                   out_left, out_right);
}

// Round 25
// 526.480 us; speedup vs baseline: 1.1904x; 1.0155x over previous
//
#include <hip/hip_runtime.h>
#include <cstdint>

#define HW 131072        // H*W
#define S_ELEMS 16777216 // B*C*H*W

typedef __attribute__((ext_vector_type(8))) _Float16 f16x8;
typedef __attribute__((ext_vector_type(4))) _Float16 f16x4;
typedef __attribute__((ext_vector_type(4))) float f32x4;

__device__ __forceinline__ float h2f(unsigned short u) {
  return (float)__builtin_bit_cast(_Float16, u);
}
__device__ __forceinline__ unsigned short f2h(float f) {
  return __builtin_bit_cast(unsigned short, (_Float16)f);
}
#define KST 72

// ---------------- BN stats stage 1: partial sums (2 sides x 64 c x 16 slabs) ----------------
__global__ __launch_bounds__(256) void bn_part_k(const float* __restrict__ xL,
                                                 const float* __restrict__ xR,
                                                 float2* __restrict__ partial) {
  int bid = blockIdx.x;
  int side = bid >> 10, rest = bid & 1023;
  int c = rest >> 4, sl = rest & 15;
  const float* x = side ? xR : xL;
  const float4* p = (const float4*)(x + ((size_t)((sl >> 3) * 64 + c)) * HW + (size_t)(sl & 7) * 16384);
  float s1 = 0.f, s2 = 0.f;
  for (int i = threadIdx.x; i < 4096; i += 256) {
    float4 v = p[i];
    s1 += v.x + v.y + v.z + v.w;
    s2 += v.x * v.x + v.y * v.y + v.z * v.z + v.w * v.w;
  }
  for (int m = 32; m; m >>= 1) {
    s1 += __shfl_xor(s1, m, 64);
    s2 += __shfl_xor(s2, m, 64);
  }
  __shared__ float r1[4], r2[4];
  int wv = threadIdx.x >> 6;
  if ((threadIdx.x & 63) == 0) { r1[wv] = s1; r2[wv] = s2; }
  __syncthreads();
  if (threadIdx.x == 0) {
    partial[bid] = make_float2(r1[0] + r1[1] + r1[2] + r1[3], r2[0] + r2[1] + r2[2] + r2[3]);
  }
}

// ---------------- BN stats stage 2: finalize scale/shift ----------------
__global__ __launch_bounds__(128) void bn_fin_k(const float2* __restrict__ partial,
                                                const float* __restrict__ gamma,
                                                const float* __restrict__ beta,
                                                float* __restrict__ stats) {
  int tid = threadIdx.x;  // 0..127: side*64 + c
  int side = tid >> 6, c = tid & 63;
  float s1 = 0.f, s2 = 0.f;
  const float2* p = partial + (side * 1024 + c * 16);
  for (int s = 0; s < 16; ++s) { float2 v = p[s]; s1 += v.x; s2 += v.y; }
  float mu = s1 / 262144.f;
  float var = s2 / 262144.f - mu * mu;
  float rs = rsqrtf(var + 1e-5f);
  float sc = rs * gamma[c];
  stats[side * 128 + c] = sc;
  stats[side * 128 + 64 + c] = beta[c] - mu * sc;
}

// ---------------- conv1 via MFMA implicit GEMM: bn(x) fp16 -> 9-tap MFMA -> leaky -> t fp16 --
// Weights fp16 (no hi/lo split): inputs are already fp16-rounded, same error class.
__global__ __launch_bounds__(256) void conv1_k(const float* __restrict__ xL,
                                               const float* __restrict__ xR,
                                               const float* __restrict__ wgt,
                                               const float* __restrict__ bias,
                                               const float* __restrict__ stats,
                                               unsigned short* __restrict__ tL,
                                               unsigned short* __restrict__ tR) {
  __shared__ __align__(16) unsigned short sInH[16 * 372];
  __shared__ __align__(16) float sW1r[2304];  // raw w1 [o][ci][9]
  __shared__ float sB1[16], sSc[16], sSh[16];
  int bid = blockIdx.x;
  int side = bid >> 12, rest = bid & 4095;
  int tw = rest & 15, th = (rest >> 4) & 31, g = (rest >> 9) & 3, b = rest >> 11;
  const float* in = side ? xR : xL;
  unsigned short* out = side ? tR : tL;
  const float* ss = stats + side * 128;
  int tid = threadIdx.x;
  const int lane = tid & 63, wv = tid >> 6;
  const int l15 = lane & 15, lg = lane >> 4;

  for (int e = tid; e < 2304; e += 256) sW1r[e] = wgt[g * 2304 + e];
  if (tid < 16) {
    sB1[tid] = bias[g * 16 + tid];
    sSc[tid] = ss[g * 16 + tid];
    sSh[tid] = ss[64 + g * 16 + tid];
  }
  __syncthreads();  // RACE FIX: sSc/sSh visible before staging reads them
  int h0 = th * 8 - 1, w0 = tw * 32 - 1;
  const float* inb = in + ((size_t)(b * 64 + g * 16)) * HW;
  for (int e = tid; e < 5440; e += 256) {
    int ci = e / 340, rem = e - ci * 340, r = rem / 34, c = rem - r * 34;
    int h = h0 + r, w = w0 + c;
    unsigned short v = 0;
    if ((unsigned)h < 256u && (unsigned)w < 512u) {
      v = f2h(inb[(size_t)ci * HW + h * 512 + w] * sSc[ci] + sSh[ci]);
    }
    sInH[ci * 372 + r * 36 + c] = v;
  }
  __syncthreads();

  f16x4 W1H[9];
#pragma unroll
  for (int tap = 0; tap < 9; ++tap) {
#pragma unroll
    for (int i = 0; i < 4; ++i)
      W1H[tap][i] = (_Float16)sW1r[l15 * 144 + (4 * lg + i) * 9 + tap];
  }
  float b14[4];
#pragma unroll
  for (int r = 0; r < 4; ++r) b14[r] = sB1[4 * lg + r];

#pragma unroll
  for (int j = 0; j < 4; ++j) {
    int ct = 4 * wv + j;
    int px = ct * 16 + l15;
    int prow = px >> 5, pcol = px & 31;
    const unsigned short* p0 = sInH + (4 * lg) * 372 + prow * 36 + pcol;
    f32x4 acc;
#pragma unroll
    for (int r = 0; r < 4; ++r) acc[r] = b14[r];
#pragma unroll
    for (int kh = 0; kh < 3; ++kh) {
#pragma unroll
      for (int kw = 0; kw < 3; ++kw) {
        int toff = kh * 36 + kw;
        f16x4 it;
#pragma unroll
        for (int i = 0; i < 4; ++i)
          it[i] = __builtin_bit_cast(_Float16, p0[i * 372 + toff]);
        acc = __builtin_amdgcn_mfma_f32_16x16x16f16(W1H[kh * 3 + kw], it, acc, 0, 0, 0);
      }
    }
    int hpix = th * 8 + prow, wpix = tw * 32 + pcol;
    size_t rowoff = (size_t)hpix * 512 + wpix;
#pragma unroll
    for (int r = 0; r < 4; ++r) {
      float a = acc[r];
      a = a > 0.f ? a : 0.1f * a;
      out[((size_t)(b * 64 + g * 16 + 4 * lg + r)) * HW + rowoff] = f2h(a);
    }
  }
}

// ---------------- fused conv2(MFMA implicit GEMM) + residual + qkv(MFMA); fp16 QKV out -----
// Weights fp16 (no hi/lo): inputs fp16-rounded already; outputs stored fp16 anyway.
__global__ __launch_bounds__(256) void conv2_qkv_k(
    const unsigned short* __restrict__ tL, const unsigned short* __restrict__ tR,
    const float* __restrict__ xL, const float* __restrict__ xR,
    const float* __restrict__ w2g, const float* __restrict__ b2g,
    const float* __restrict__ wq, const float* __restrict__ bq,
    const float* __restrict__ stats,
    unsigned short* __restrict__ qnL, unsigned short* __restrict__ qnR,
    unsigned short* __restrict__ knL, unsigned short* __restrict__ knR,
    unsigned short* __restrict__ vnL, unsigned short* __restrict__ vnR) {
  __shared__ __align__(16) unsigned short sInH[16 * 372];
  __shared__ __align__(16) float sW2r[2304];
  __shared__ __align__(16) float sWq[768];
  __shared__ float sB2[16], sBq[48], sSc[16], sSh[16];

  int bid = blockIdx.x;
  int side = bid >> 12, rest = bid & 4095;
  int tw = rest & 15, th = (rest >> 4) & 31, g = (rest >> 9) & 3, b = rest >> 11;
  const unsigned short* t = side ? tR : tL;
  const float* x = side ? xR : xL;
  unsigned short* qn = side ? qnR : qnL;
  unsigned short* kn = side ? knR : knL;
  unsigned short* vn = side ? vnR : vnL;
  const float* ss = stats + side * 128;
  int tid = threadIdx.x;
  const int lane = tid & 63, wv = tid >> 6;
  const int l15 = lane & 15, lg = lane >> 4;

  float resx[4][4];
#pragma unroll
  for (int j = 0; j < 4; ++j) {
    int px = (4 * wv + j) * 16 + l15;
    int hpix = th * 8 + (px >> 5), wpix = tw * 32 + (px & 31);
    size_t rowoff = (size_t)hpix * 512 + wpix;
#pragma unroll
    for (int r = 0; r < 4; ++r)
      resx[j][r] = x[((size_t)(b * 64 + g * 16 + 4 * lg + r)) * HW + rowoff];
  }

  for (int e = tid; e < 2304; e += 256) sW2r[e] = w2g[g * 2304 + e];
  for (int e = tid; e < 768; e += 256) {
    int oo = e >> 4, ci = e & 15;
    sWq[e] = wq[(g * 48 + oo) * 16 + ci];
  }
  if (tid < 48) sBq[tid] = bq[g * 48 + tid];
  if (tid < 16) {
    sB2[tid] = b2g[g * 16 + tid];
    sSc[tid] = ss[g * 16 + tid];
    sSh[tid] = ss[64 + g * 16 + tid];
  }

  int h0 = th * 8 - 1, w0 = tw * 32 - 1;
  const unsigned short* inb = t + ((size_t)(b * 64 + g * 16)) * HW;
  for (int e = tid; e < 5440; e += 256) {
    int ci = e / 340, rem = e - ci * 340, r = rem / 34, c = rem - r * 34;
    int h = h0 + r, w = w0 + c;
    unsigned short v = 0;
    if ((unsigned)h < 256u && (unsigned)w < 512u) {
      v = inb[(size_t)ci * HW + h * 512 + w];
    }
    sInH[ci * 372 + r * 36 + c] = v;
  }
  __syncthreads();

  f16x4 W2H[9];
#pragma unroll
  for (int tap = 0; tap < 9; ++tap) {
#pragma unroll
    for (int i = 0; i < 4; ++i)
      W2H[tap][i] = (_Float16)sW2r[l15 * 144 + (4 * lg + i) * 9 + tap];
  }
  f16x4 WqH[3];
#pragma unroll
  for (int rt = 0; rt < 3; ++rt) {
    float4 wvv = *(const float4*)(sWq + (rt * 16 + l15) * 16 + 4 * lg);
#pragma unroll
    for (int i = 0; i < 4; ++i)
      WqH[rt][i] = (_Float16)((float*)&wvv)[i];
  }
  float sc4[4], sh4[4], b24[4];
#pragma unroll
  for (int r = 0; r < 4; ++r) {
    sc4[r] = sSc[4 * lg + r];
    sh4[r] = sSh[4 * lg + r];
    b24[r] = sB2[4 * lg + r];
  }

#pragma unroll
  for (int j = 0; j < 4; ++j) {
    int ct = 4 * wv + j;
    int px = ct * 16 + l15;
    int prow = px >> 5, pcol = px & 31;
    const unsigned short* p0 = sInH + (4 * lg) * 372 + prow * 36 + pcol;
    f32x4 acc;
#pragma unroll
    for (int r = 0; r < 4; ++r) acc[r] = b24[r];
#pragma unroll
    for (int kh = 0; kh < 3; ++kh) {
#pragma unroll
      for (int kw = 0; kw < 3; ++kw) {
        int toff = kh * 36 + kw;
        f16x4 it;
#pragma unroll
        for (int i = 0; i < 4; ++i)
          it[i] = __builtin_bit_cast(_Float16, p0[i * 372 + toff]);
        acc = __builtin_amdgcn_mfma_f32_16x16x16f16(W2H[kh * 3 + kw], it, acc, 0, 0, 0);
      }
    }
#pragma unroll
    for (int r = 0; r < 4; ++r) acc[r] += resx[j][r] * sc4[r] + sh4[r];
    // r fragment (conv2 D == qkv B mapping: lane holds ci=4lg+i at px)
    f16x4 rh;
#pragma unroll
    for (int i = 0; i < 4; ++i) rh[i] = (_Float16)acc[i];
    int hpix = th * 8 + prow, wpix = tw * 32 + pcol;
    size_t pxbase = ((size_t)b * HW + hpix * 512 + wpix) * 64;
#pragma unroll
    for (int rt = 0; rt < 3; ++rt) {
      f32x4 a;
#pragma unroll
      for (int r = 0; r < 4; ++r) a[r] = sBq[rt * 16 + 4 * lg + r];
      a = __builtin_amdgcn_mfma_f32_16x16x16f16(WqH[rt], rh, a, 0, 0, 0);
      int ob = g * 48 + rt * 16 + 4 * lg;
      uint2 pk;
      pk.x = (uint32_t)f2h(a[0]) | ((uint32_t)f2h(a[1]) << 16);
      pk.y = (uint32_t)f2h(a[2]) | ((uint32_t)f2h(a[3]) << 16);
      if (ob < 64) {
        *(uint2*)(qn + pxbase + ob) = pk;
      } else if (ob < 128) {
        *(uint2*)(kn + pxbase + (ob - 64)) = pk;
      } else {
        *(uint2*)(vn + pxbase + (ob - 128)) = pk;
      }
    }
  }
}

// ---------------- fused per-window attention: all-fp16 QKV, fp16 M ----
__global__ __launch_bounds__(256, 4) void attn_k(
    const unsigned short* __restrict__ qLn, const unsigned short* __restrict__ qRn,  // NHWC fp16
    const unsigned short* __restrict__ kLn, const unsigned short* __restrict__ kRn,  // NHWC fp16
    const unsigned short* __restrict__ vLn, const unsigned short* __restrict__ vRn,  // NHWC fp16
    const float* __restrict__ dL, const float* __restrict__ dR,
    const float* __restrict__ xL, const float* __restrict__ xR,
    float* outL, float* outR) {
  // XCD-aware swizzle: consecutive windows -> same XCD L2 (4096 % 8 == 0, bijective)
  const int orig = blockIdx.x;
  const int n = (orig & 7) * 512 + (orig >> 3);
  const int b = n >> 11, hb = (n >> 6) & 31, wb = n & 63;
  const int tid = threadIdx.x;
  const int lane = tid & 63, w = tid >> 6;
  const int l15 = lane & 15, lg = lane >> 4;

  // K fp16 (stride 72) per dir; region reused after B2.5 as fp16 M (stride 72).
  __shared__ __align__(16) unsigned short sK[2 * 64 * KST];  // 18432 B
  __shared__ float meanA[8], meanB[8], qsA[64], qsB[64], mapL[64], mapR[64];
  unsigned short* KHA = sK;
  unsigned short* KHB = sK + 64 * KST;
  unsigned short* MHA = sK;            // fp16 M overlay, stride 72
  unsigned short* MHB = sK + 64 * KST;

  const float* dLb = dL + (size_t)b * HW;
  const float* dRb = dR + (size_t)b * HW;
  const size_t nb = (size_t)b * HW;

  // ---- K gather (NHWC fp16): 2 iters, one b128 per thread per dir ----
  const int cc0 = (wb & 7) * 8;
#pragma unroll
  for (int it = 0; it < 2; ++it) {
    int slot = tid + 256 * it;           // 0..511
    int c2 = slot & 63, k8 = slot >> 6;  // k8 0..7
    int hh = 4 * c2 + (hb >> 3);
    int ww = (hb & 7) * 64 + k8 * 8 + (wb >> 3);
    int dpos = hh * 512 + ww;
    int iwr = ww - (int)dLb[dpos]; iwr = min(max(iwr, 0), 511);
    int iwl = ww + (int)dRb[dpos]; iwl = min(max(iwl, 0), 511);
    int4 kr = *(const int4*)(kRn + (nb + hh * 512 + iwr) * 64 + cc0);
    int4 kl = *(const int4*)(kLn + (nb + hh * 512 + iwl) * 64 + cc0);
    const unsigned short* krp = (const unsigned short*)&kr;
    const unsigned short* klp = (const unsigned short*)&kl;
#pragma unroll
    for (int kl2 = 0; kl2 < 8; ++kl2) {
      int k = 8 * k8 + kl2;
      KHA[k * KST + c2] = krp[kl2];
      KHB[k * KST + c2] = klp[kl2];
    }
  }

  // ---- Q fragments (NHWC fp16: direct b128 loads) ----
  const int jr = 16 * w + l15;
  const int hp = hb * 8 + (jr >> 3), wp = wb * 8 + (jr & 7);
  const int gpix = hp * 512 + wp;
  const unsigned short* qlp = qLn + (nb + (size_t)gpix) * 64;
  const unsigned short* qrp = qRn + (nb + (size_t)gpix) * 64;
  f16x8 qa0 = *(const f16x8*)(qlp + 8 * lg);
  f16x8 qa1 = *(const f16x8*)(qlp + 32 + 8 * lg);
  f16x8 qb0 = *(const f16x8*)(qrp + 8 * lg);
  f16x8 qb1 = *(const f16x8*)(qrp + 32 + 8 * lg);

  // ---- V fragments (NHWC fp16: one b128 per (h,dir)) ----
  int4 vAr[2], vBr[2];
  {
    const int cv = 16 * w + l15;
#pragma unroll
    for (int h = 0; h < 2; ++h) {
      int hi = 4 * h + lg;
      int hh = 4 * cv + (hb >> 3);
      int ww = (hb & 7) * 64 + hi * 8 + (wb >> 3);
      int dpos = hh * 512 + ww;
      int iwr = ww - (int)dLb[dpos]; iwr = min(max(iwr, 0), 511);
      int iwl = ww + (int)dRb[dpos]; iwl = min(max(iwl, 0), 511);
      vAr[h] = *(const int4*)(vRn + (nb + hh * 512 + iwr) * 64 + cc0);
      vBr[h] = *(const int4*)(vLn + (nb + hh * 512 + iwl) * 64 + cc0);
    }
  }
  __syncthreads();  // B1: K staged

  // ---- K means per (dir,hi) over (wi,c) from the SAME rounded K the MFMA sees ----
  {
    int grp = tid >> 4, i = tid & 15;
    int dir = grp >> 3, hi = grp & 7;
    int off0 = (8 * hi + (i >> 1)) * KST + (i & 1) * 32;
    const unsigned short* srcH = (dir ? KHB : KHA) + off0;
    float s = 0.f;
#pragma unroll
    for (int q = 0; q < 32; ++q) s += h2f(srcH[q]);
    for (int m = 8; m; m >>= 1) s += __shfl_xor(s, m, 64);
    if (i == 0) (dir ? meanB : meanA)[hi] = s * (1.f / 512.f);
  }
  // ---- qsum[j] from the SAME rounded q the MFMA sees ----
  {
    float sa = 0.f, sb = 0.f;
#pragma unroll
    for (int e = 0; e < 8; ++e) {
      sa += (float)qa0[e] + (float)qa1[e];
      sb += (float)qb0[e] + (float)qb1[e];
    }
    sa += __shfl_xor(sa, 16, 64); sa += __shfl_xor(sa, 32, 64);
    sb += __shfl_xor(sb, 16, 64); sb += __shfl_xor(sb, 32, 64);
    if (lane < 16) { qsA[jr] = sa; qsB[jr] = sb; }
  }
  __syncthreads();  // B2: means + qsums ready

  // ---- QK^T: q16 . k16 -> 1 MFMA per K-chunk per dir ----
  f32x4 sA[4], sB[4];
#pragma unroll
  for (int t = 0; t < 4; ++t) { sA[t] = (f32x4){0.f, 0.f, 0.f, 0.f}; sB[t] = sA[t]; }
#pragma unroll
  for (int t = 0; t < 4; ++t) {
    int ro = (16 * t + l15) * KST + 8 * lg;
    f16x8 kh0 = *(const f16x8*)(KHA + ro);
    f16x8 kh1 = *(const f16x8*)(KHA + ro + 32);
    sA[t] = __builtin_amdgcn_mfma_f32_16x16x32_f16(qa0, kh0, sA[t], 0, 0, 0);
    sA[t] = __builtin_amdgcn_mfma_f32_16x16x32_f16(qa1, kh1, sA[t], 0, 0, 0);
    f16x8 mh0 = *(const f16x8*)(KHB + ro);
    f16x8 mh1 = *(const f16x8*)(KHB + ro + 32);
    sB[t] = __builtin_amdgcn_mfma_f32_16x16x32_f16(qb0, mh0, sB[t], 0, 0, 0);
    sB[t] = __builtin_amdgcn_mfma_f32_16x16x32_f16(qb1, mh1, sB[t], 0, 0, 0);
  }
  // ---- mean-fold correction + in-register softmax over k ----
  {
    float qra[4], qrb2[4];
#pragma unroll
    for (int reg = 0; reg < 4; ++reg) {
      qra[reg] = qsA[16 * w + 4 * lg + reg];
      qrb2[reg] = qsB[16 * w + 4 * lg + reg];
    }
#pragma unroll
    for (int t = 0; t < 4; ++t) {
      float mA_ = meanA[2 * t + (l15 >> 3)];
      float mB_ = meanB[2 * t + (l15 >> 3)];
#pragma unroll
      for (int reg = 0; reg < 4; ++reg) {
        sA[t][reg] -= qra[reg] * mA_;
        sB[t][reg] -= qrb2[reg] * mB_;
      }
    }
#pragma unroll
    for (int reg = 0; reg < 4; ++reg) {
      float ma = sA[0][reg], mb = sB[0][reg];
#pragma unroll
      for (int t = 1; t < 4; ++t) { ma = fmaxf(ma, sA[t][reg]); mb = fmaxf(mb, sB[t][reg]); }
#pragma unroll
      for (int m = 1; m <= 8; m <<= 1) {
        ma = fmaxf(ma, __shfl_xor(ma, m, 64));
        mb = fmaxf(mb, __shfl_xor(mb, m, 64));
      }
      float sa = 0.f, sb = 0.f;
#pragma unroll
      for (int t = 0; t < 4; ++t) {
        float ea = __expf(sA[t][reg] - ma), eb = __expf(sB[t][reg] - mb);
        sA[t][reg] = ea; sB[t][reg] = eb;
        sa += ea; sb += eb;
      }
#pragma unroll
      for (int m = 1; m <= 8; m <<= 1) {
        sa += __shfl_xor(sa, m, 64);
        sb += __shfl_xor(sb, m, 64);
      }
      float ra = 1.f / sa, rb = 1.f / sb;
#pragma unroll
      for (int t = 0; t < 4; ++t) { sA[t][reg] *= ra; sB[t][reg] *= rb; }
    }
  }
  __syncthreads();  // B2.5: all K reads done; overlay fp16 M onto K region

  // ---- write M fp16 (stride 72; PV fragment layout) ----
#pragma unroll
  for (int t = 0; t < 4; ++t)
#pragma unroll
    for (int reg = 0; reg < 4; ++reg) {
      int jrow = 16 * w + 4 * lg + reg, kcol = 16 * t + l15;
      MHA[jrow * KST + kcol] = f2h(sA[t][reg]);
      MHB[jrow * KST + kcol] = f2h(sB[t][reg]);
    }
  __syncthreads();  // B3: M complete

  // ---- PV via MFMA: X^T[c][j] = sum_k V_sel[k][c] * M[j][k] ----
  f32x4 pL[4], pR[4];
#pragma unroll
  for (int t = 0; t < 4; ++t) { pL[t] = (f32x4){0.f, 0.f, 0.f, 0.f}; pR[t] = pL[t]; }
#pragma unroll
  for (int h = 0; h < 2; ++h) {
    f16x8 va = __builtin_bit_cast(f16x8, vAr[h]);
    f16x8 vb = __builtin_bit_cast(f16x8, vBr[h]);
#pragma unroll
    for (int jt = 0; jt < 4; ++jt) {
      f16x8 ma = *(const f16x8*)(MHA + (16 * jt + l15) * KST + 32 * h + 8 * lg);
      f16x8 mb = *(const f16x8*)(MHB + (16 * jt + l15) * KST + 32 * h + 8 * lg);
      pL[jt] = __builtin_amdgcn_mfma_f32_16x16x32_f16(va, ma, pL[jt], 0, 0, 0);
      pR[jt] = __builtin_amdgcn_mfma_f32_16x16x32_f16(vb, mb, pR[jt], 0, 0, 0);
    }
  }
  // ---- x blend prefetch (T14): issue loads before m_relax, use after B4 ----
  float xlv[4][4], xrv[4][4];
#pragma unroll
  for (int jt = 0; jt < 4; ++jt)
#pragma unroll
    for (int reg = 0; reg < 4; ++reg) {
      int c = 16 * w + 4 * lg + reg;
      int j = 16 * jt + l15;
      int hp2 = hb * 8 + (j >> 3), wp2 = wb * 8 + (j & 7);
      size_t off = ((size_t)(b * 64 + c)) * HW + hp2 * 512 + wp2;
      xlv[jt][reg] = xL[off];
      xrv[jt][reg] = xR[off];
    }
  // ---- m_relax band + einsum + tanh from fp16 M (128 threads) ----
  if (tid < 128) {
    int dir = tid >> 6, j = tid & 63;
    const unsigned short* Mrow = dir ? MHB : MHA;
    const unsigned short* Mcol = dir ? MHA : MHB;
    float acc = 0.f;
    for (int k = 0; k < 64; ++k) {
      float rx = 0.f;
#pragma unroll
      for (int i = -2; i <= 2; ++i) {
        int jj = j + i;
        if ((unsigned)jj < 64u) rx += h2f(Mrow[jj * KST + k]);
      }
      acc += rx * h2f(Mcol[k * KST + j]);
    }
    (dir ? mapR : mapL)[j] = tanhf(5.f * acc);
  }
  __syncthreads();  // B4: maps ready

  // ---- blend + store ----
#pragma unroll
  for (int jt = 0; jt < 4; ++jt) {
#pragma unroll
    for (int reg = 0; reg < 4; ++reg) {
      int c = 16 * w + 4 * lg + reg;
      int j = 16 * jt + l15;
      int hp2 = hb * 8 + (j >> 3), wp2 = wb * 8 + (j & 7);
      size_t off = ((size_t)(b * 64 + c)) * HW + hp2 * 512 + wp2;
      float ml = mapL[j], mr = mapR[j];
      outL[off] = xlv[jt][reg] * (1.f - ml) + pL[jt][reg] * ml;
      outR[off] = xrv[jt][reg] * (1.f - mr) + pR[jt][reg] * mr;
    }
  }
}

extern "C" void kernel_launch(void* const* d_in, const int* in_sizes, int n_in,
                              void* d_out, int out_size, void* d_ws, size_t ws_size,
                              hipStream_t stream) {
  const float* x_left = (const float*)d_in[0];
  const float* x_right = (const float*)d_in[1];
  const float* d_left = (const float*)d_in[2];
  const float* d_right = (const float*)d_in[3];
  const float* bn_gamma = (const float*)d_in[4];
  const float* bn_beta = (const float*)d_in[5];
  const float* rb_w1 = (const float*)d_in[6];
  const float* rb_b1 = (const float*)d_in[7];
  const float* rb_w2 = (const float*)d_in[8];
  const float* rb_b2 = (const float*)d_in[9];
  const float* qkv_w = (const float*)d_in[10];
  const float* qkv_b = (const float*)d_in[11];

  float* ws = (float*)d_ws;
  const size_t S = S_ELEMS;
  unsigned short* tL = (unsigned short*)ws;               // [0,S) floats: t fp16 both sides
  unsigned short* tR = tL + S;
  unsigned short* qnL = (unsigned short*)(ws + S);        // [S,2S): Q fp16 NHWC
  unsigned short* qnR = qnL + S;
  unsigned short* knL = (unsigned short*)(ws + 2 * S);    // [2S,3S): K fp16 NHWC
  unsigned short* knR = knL + S;
  unsigned short* vnL = (unsigned short*)(ws + 3 * S);    // [3S,4S): V fp16 NHWC
  unsigned short* vnR = vnL + S;

  // partial/stats at head of d_out: written by bn kernels, read by conv kernels,
  // overwritten by attn's blend at the end (stream order guarantees safety).
  float* out_left = (float*)d_out;
  float* out_right = out_left + S;
  float2* partial = (float2*)d_out;              // 2048 float2
  float* stats = (float*)d_out + 4096;           // 256 floats

  bn_part_k<<<2048, 256, 0, stream>>>(x_left, x_right, partial);
  bn_fin_k<<<1, 128, 0, stream>>>(partial, bn_gamma, bn_beta, stats);

  conv1_k<<<8192, 256, 0, stream>>>(x_left, x_right, rb_w1, rb_b1, stats, tL, tR);
  conv2_qkv_k<<<8192, 256, 0, stream>>>(tL, tR, x_left, x_right, rb_w2, rb_b2,
                                        qkv_w, qkv_b, stats,
                                        qnL, qnR, knL, knR, vnL, vnR);
  attn_k<<<4096, 256, 0, stream>>>(qnL, qnR, knL, knR, vnL, vnR,
                                   d_left, d_right, x_left, x_right,
                                   out_left, out_right);
}